// Round 1
// baseline (476.624 us; speedup 1.0000x reference)
//
#include <hip/hip_runtime.h>
#include <math.h>

#define NN 20000     // nodes
#define NE 320000    // edges
#define NR 500       // relations
#define EMBD 256
#define D4 64
#define BQ 32        // batch

// ---------------- small param kernels ----------------

__global__ void k_params(const float* __restrict__ bO1, const float* __restrict__ bI1,
                         const float* __restrict__ bS1,
                         const float* __restrict__ g1, const float* __restrict__ bb1,
                         const float* __restrict__ m1, const float* __restrict__ v1,
                         const float* __restrict__ bO2, const float* __restrict__ bI2,
                         const float* __restrict__ bS2,
                         const float* __restrict__ g2, const float* __restrict__ bb2,
                         const float* __restrict__ m2, const float* __restrict__ v2,
                         float* __restrict__ s1, float* __restrict__ t1,
                         float* __restrict__ s2, float* __restrict__ t2)
{
    int i = blockIdx.x * 256 + threadIdx.x;
    if (i < 64) {
        float rsg = g1[i] / sqrtf(v1[i] + 1e-5f);
        s1[i] = rsg * (1.f / 3.f);
        t1[i] = ((bO1[i] + bI1[i] + bS1[i]) * (1.f / 3.f) - m1[i]) * rsg + bb1[i];
    } else if (i < 64 + 256) {
        int n = i - 64;
        float rsg = g2[n] / sqrtf(v2[n] + 1e-5f);
        s2[n] = rsg * (1.f / 3.f);
        t2[n] = ((bO2[n] + bI2[n] + bS2[n]) * (1.f / 3.f) - m2[n]) * rsg + bb2[n];
    }
}

// Build k-major weight blocks:
// Bt1[k][n], 256x256: n<64 W_O1[n][k]; <128 W_I1; <192 W_S1; <256 Wr1
// Bt2[k][n], 192x256: k<64 W_O2[n][k]; <128 W_I2[n][k-64]; <192 W_S2[n][k-128]
__global__ void k_buildBt(const float* __restrict__ W_O1, const float* __restrict__ W_I1,
                          const float* __restrict__ W_S1, const float* __restrict__ Wr1,
                          const float* __restrict__ W_O2, const float* __restrict__ W_I2,
                          const float* __restrict__ W_S2,
                          float* __restrict__ Bt1, float* __restrict__ Bt2)
{
    int id = blockIdx.x * 256 + threadIdx.x;
    if (id < 256 * 256) {
        int k = id >> 8, n = id & 255;
        float v;
        if (n < 64)       v = W_O1[n * 256 + k];
        else if (n < 128) v = W_I1[(n - 64) * 256 + k];
        else if (n < 192) v = W_S1[(n - 128) * 256 + k];
        else              v = Wr1[(n - 192) * 256 + k];
        Bt1[id] = v;
    } else {
        int id2 = id - 256 * 256;
        if (id2 < 192 * 256) {
            int k = id2 >> 8, n = id2 & 255;
            float v;
            if (k < 64)       v = W_O2[n * 64 + k];
            else if (k < 128) v = W_I2[n * 64 + (k - 64)];
            else              v = W_S2[n * 64 + (k - 128)];
            Bt2[id2] = v;
        }
    }
}

__global__ void k_deg(const int* __restrict__ src, const int* __restrict__ dst,
                      float* __restrict__ degi, float* __restrict__ dego)
{
    int i = blockIdx.x * 256 + threadIdx.x;
    if (i < NE) {
        atomicAdd(&degi[dst[i]], 1.f);
        atomicAdd(&dego[src[i]], 1.f);
    }
}

__global__ void k_invdeg(float* __restrict__ degi, float* __restrict__ dego)
{
    int n = blockIdx.x * 256 + threadIdx.x;
    if (n < NN) {
        degi[n] = 1.f / fmaxf(degi[n], 1.f);
        dego[n] = 1.f / fmaxf(dego[n], 1.f);
    }
}

// er1 = tanh(raw + br1), in place on E1 cols [192,256)
__global__ void k_er1(float* __restrict__ E1, const float* __restrict__ br1)
{
    int id = blockIdx.x * 256 + threadIdx.x;
    if (id >= NR * 64) return;
    int r = id >> 6, j = id & 63;
    float v = E1[r * 256 + 192 + j];
    E1[r * 256 + 192 + j] = tanhf(v + br1[j]);
}

// ---------------- tiled f32 GEMM: C = A @ Bt  (Bt is [K][N] k-major) ----------------
// mode 0: raw store to C (ldc). mode 2: hn epilogue tanh(acc*sv[n]+tv[n]) (or node_embs if !flag)
__global__ __launch_bounds__(256) void gemm64(
    const float* __restrict__ A, int M, int K, int lda,
    const float* __restrict__ Bt, int ldb,
    float* __restrict__ C, int ldc, int mode,
    const float* __restrict__ sv, const float* __restrict__ tv,
    const float* __restrict__ node_embs, const int* __restrict__ flag)
{
    __shared__ float As[64][68];   // k-major: As[k][m]
    __shared__ float Bs[64][68];   // Bs[k][n]
    const int t = threadIdx.x;
    const int m0 = blockIdx.x * 64, n0 = blockIdx.y * 64;
    const int tn = t & 15, to = t >> 4;
    float acc[4][4] = {};

    for (int kb = 0; kb < K; kb += 64) {
#pragma unroll
        for (int it = 0; it < 4; ++it) {
            int idx = t + it * 256;          // [0,1024)
            int kq = idx & 15;               // k-quad
            int m = idx >> 4;                // row (A) / k (B)
            int gm = m0 + m;
            float4 a = make_float4(0.f, 0.f, 0.f, 0.f);
            if (gm < M) a = *(const float4*)(A + (size_t)gm * lda + kb + 4 * kq);
            As[4 * kq + 0][m] = a.x;
            As[4 * kq + 1][m] = a.y;
            As[4 * kq + 2][m] = a.z;
            As[4 * kq + 3][m] = a.w;
            float4 b = *(const float4*)(Bt + (size_t)(kb + m) * ldb + n0 + 4 * kq);
            *(float4*)&Bs[m][4 * kq] = b;
        }
        __syncthreads();
#pragma unroll 8
        for (int kk = 0; kk < 64; ++kk) {
            float4 av = *(const float4*)&As[kk][4 * tn];
            float4 bv = *(const float4*)&Bs[kk][4 * to];
            float a0 = av.x, a1 = av.y, a2 = av.z, a3 = av.w;
            float b0 = bv.x, b1 = bv.y, b2 = bv.z, b3 = bv.w;
            acc[0][0] = fmaf(a0, b0, acc[0][0]); acc[0][1] = fmaf(a0, b1, acc[0][1]);
            acc[0][2] = fmaf(a0, b2, acc[0][2]); acc[0][3] = fmaf(a0, b3, acc[0][3]);
            acc[1][0] = fmaf(a1, b0, acc[1][0]); acc[1][1] = fmaf(a1, b1, acc[1][1]);
            acc[1][2] = fmaf(a1, b2, acc[1][2]); acc[1][3] = fmaf(a1, b3, acc[1][3]);
            acc[2][0] = fmaf(a2, b0, acc[2][0]); acc[2][1] = fmaf(a2, b1, acc[2][1]);
            acc[2][2] = fmaf(a2, b2, acc[2][2]); acc[2][3] = fmaf(a2, b3, acc[2][3]);
            acc[3][0] = fmaf(a3, b0, acc[3][0]); acc[3][1] = fmaf(a3, b1, acc[3][1]);
            acc[3][2] = fmaf(a3, b2, acc[3][2]); acc[3][3] = fmaf(a3, b3, acc[3][3]);
        }
        __syncthreads();
    }

#pragma unroll
    for (int i = 0; i < 4; ++i) {
        int gm = m0 + 4 * tn + i;
        if (gm >= M) continue;
#pragma unroll
        for (int j = 0; j < 4; ++j) {
            int gn = n0 + 4 * to + j;
            float v = acc[i][j];
            if (mode == 0) {
                C[(size_t)gm * ldc + gn] = v;
            } else {
                float val = tanhf(v * sv[gn] + tv[gn]);
                if (flag[0] == 0) val = node_embs[(size_t)gm * EMBD + gn];
                C[(size_t)gm * EMBD + gn] = val;
            }
        }
    }
}

// ---------------- edge aggregation (one wave per edge, 64 dims) ----------------
__global__ __launch_bounds__(256) void k_agg(
    const int* __restrict__ src, const int* __restrict__ dst, const int* __restrict__ evid,
    const float* __restrict__ HN, int ldh, int hoffO, int hoffI,
    const float* __restrict__ EV, int lde, int eoffO, int eoffI,
    const float* __restrict__ invdeg_in, const float* __restrict__ invdeg_out,
    float* __restrict__ AG, int ldg, int goffO, int goffI)
{
    int e = blockIdx.x * 4 + (threadIdx.x >> 6);
    if (e >= NE) return;
    int j = threadIdx.x & 63;
    int s = src[e], d = dst[e], r = evid[e];
    float vO = HN[(size_t)s * ldh + hoffO + j] - EV[(size_t)r * lde + eoffO + j];
    float vI = HN[(size_t)d * ldh + hoffI + j] - EV[(size_t)r * lde + eoffI + j];
    atomicAdd(&AG[(size_t)d * ldg + goffO + j], vO * invdeg_in[d]);
    atomicAdd(&AG[(size_t)s * ldg + goffI + j], vI * invdeg_out[s]);
}

// combine layer-1: h1 = tanh((aggO'+aggI'+hS1raw)*s1 + t1) -> A2 cols [128,192)
__global__ void k_combine1(const float* __restrict__ agg1, const float* __restrict__ C1,
                           const float* __restrict__ s1, const float* __restrict__ t1,
                           float* __restrict__ A2)
{
    int id = blockIdx.x * 256 + threadIdx.x;
    if (id >= NN * 64) return;
    int n = id >> 6, j = id & 63;
    float x = agg1[(size_t)n * 128 + j] + agg1[(size_t)n * 128 + 64 + j]
            + C1[(size_t)n * 192 + 128 + j];
    A2[(size_t)n * 192 + 128 + j] = tanhf(x * s1[j] + t1[j]);
}

// ---------------- scoring ----------------
// t[b] = is_head ? hn[tids[b]] - rels[b] : hn[hids[b]] + rels[b]
// rels = relu(edge_embs[rids] @ Wr1^T + br1) @ Wr2^T + br2
__global__ __launch_bounds__(64) void k_rels(
    const float* __restrict__ edge_embs,
    const float* __restrict__ Wr1, const float* __restrict__ br1,
    const float* __restrict__ Wr2, const float* __restrict__ br2,
    const int* __restrict__ hids, const int* __restrict__ rids, const int* __restrict__ tids,
    const int* __restrict__ is_head, const float* __restrict__ hn,
    float* __restrict__ tvec)
{
    __shared__ float e_s[256];
    __shared__ float m_s[64];
    int b = blockIdx.x, o = threadIdx.x;
    int rid = rids[b];
#pragma unroll
    for (int q = 0; q < 4; ++q) e_s[o + 64 * q] = edge_embs[(size_t)rid * 256 + o + 64 * q];
    __syncthreads();
    float acc = br1[o];
    for (int k = 0; k < 256; ++k) acc = fmaf(e_s[k], Wr1[o * 256 + k], acc);
    m_s[o] = fmaxf(acc, 0.f);
    __syncthreads();
    int ih = is_head[0];
    int nid = ih ? tids[b] : hids[b];
#pragma unroll
    for (int q = 0; q < 4; ++q) {
        int n = o + 64 * q;
        float r = br2[n];
        for (int jj = 0; jj < 64; ++jj) r = fmaf(m_s[jj], Wr2[n * 64 + jj], r);
        float hv = hn[(size_t)nid * 256 + n];
        tvec[b * 256 + n] = ih ? (hv - r) : (hv + r);
    }
}

// one wave per (b, group j): dist over 256 dims, fan out to 32 identical scores
__global__ __launch_bounds__(256) void k_score(
    const float* __restrict__ hn, const float* __restrict__ tvec,
    float* __restrict__ score)
{
    int p = blockIdx.x * 4 + (threadIdx.x >> 6);
    if (p >= BQ * (NN / BQ)) return;
    int l = threadIdx.x & 63;
    int b = p / (NN / BQ);
    int j = p - b * (NN / BQ);
    int idx = (b * NN + 32 * j) / BQ;   // faithful repeat_interleave indexing
    float ssum = 0.f;
#pragma unroll
    for (int q = 0; q < 4; ++q) {
        float df = hn[(size_t)idx * 256 + l + 64 * q] - tvec[b * 256 + l + 64 * q];
        ssum = fmaf(df, df, ssum);
    }
#pragma unroll
    for (int off = 32; off >= 1; off >>= 1) ssum += __shfl_xor(ssum, off, 64);
    float dist = sqrtf(ssum);
    float sc = 1.f / (1.f + expf(dist - 12.f));
    if (l < 32) score[(size_t)b * NN + 32 * j + l] = sc;
}

// ---------------- launch ----------------
extern "C" void kernel_launch(void* const* d_in, const int* in_sizes, int n_in,
                              void* d_out, int out_size, void* d_ws, size_t ws_size,
                              hipStream_t stream)
{
    const float* node_embs = (const float*)d_in[0];
    const float* edge_embs = (const float*)d_in[1];
    const float* W_O1 = (const float*)d_in[2];  const float* b_O1 = (const float*)d_in[3];
    const float* W_I1 = (const float*)d_in[4];  const float* b_I1 = (const float*)d_in[5];
    const float* W_S1 = (const float*)d_in[6];  const float* b_S1 = (const float*)d_in[7];
    const float* bn1_g = (const float*)d_in[8]; const float* bn1_b = (const float*)d_in[9];
    const float* bn1_m = (const float*)d_in[10];const float* bn1_v = (const float*)d_in[11];
    const float* Wr1 = (const float*)d_in[12];  const float* br1 = (const float*)d_in[13];
    const float* W_O2 = (const float*)d_in[14]; const float* b_O2 = (const float*)d_in[15];
    const float* W_I2 = (const float*)d_in[16]; const float* b_I2 = (const float*)d_in[17];
    const float* W_S2 = (const float*)d_in[18]; const float* b_S2 = (const float*)d_in[19];
    const float* bn2_g = (const float*)d_in[20];const float* bn2_b = (const float*)d_in[21];
    const float* bn2_m = (const float*)d_in[22];const float* bn2_v = (const float*)d_in[23];
    const float* Wr2 = (const float*)d_in[24];  const float* br2 = (const float*)d_in[25];
    const int* src = (const int*)d_in[26];
    const int* dst = (const int*)d_in[27];
    const int* evid = (const int*)d_in[28];
    const int* hids = (const int*)d_in[29];
    const int* rids = (const int*)d_in[30];
    const int* tids = (const int*)d_in[31];
    const int* upd = (const int*)d_in[32];
    const int* ihead = (const int*)d_in[33];

    float* ws = (float*)d_ws;
    float* C1   = ws;                      // 20000*192  : [hO1 | hI1 | hS1raw]
    float* A2   = C1 + 3840000;            // 20000*192  : [agg2O' | agg2I' | h1]
    float* agg1 = A2 + 3840000;            // 20000*128  : [aggO' | aggI']
    float* E1   = agg1 + 2560000;          // 500*256    : [eO1 | eI1 | (unused) | er1]
    float* Bt1  = E1 + 128000;             // 256*256
    float* Bt2  = Bt1 + 65536;             // 192*256
    float* degi = Bt2 + 49152;             // 20000 (-> invdeg_in)
    float* dego = degi + 20000;            // 20000 (-> invdeg_out)
    float* s1   = dego + 20000;            // 64
    float* t1   = s1 + 64;                 // 64
    float* s2   = t1 + 64;                 // 256
    float* t2   = s2 + 256;                // 256
    float* tvec = t2 + 256;                // 32*256

    float* hn    = (float*)d_out;                       // 20000*256
    float* score = hn + (size_t)NN * EMBD;              // 32*20000

    hipMemsetAsync(agg1, 0, (size_t)2560000 * 4, stream);
    hipMemsetAsync(A2,   0, (size_t)3840000 * 4, stream);
    hipMemsetAsync(degi, 0, (size_t)2 * 20000 * 4, stream);

    k_params<<<2, 256, 0, stream>>>(b_O1, b_I1, b_S1, bn1_g, bn1_b, bn1_m, bn1_v,
                                    b_O2, b_I2, b_S2, bn2_g, bn2_b, bn2_m, bn2_v,
                                    s1, t1, s2, t2);
    k_buildBt<<<(256 * 256 + 192 * 256 + 255) / 256, 256, 0, stream>>>(
        W_O1, W_I1, W_S1, Wr1, W_O2, W_I2, W_S2, Bt1, Bt2);
    k_deg<<<(NE + 255) / 256, 256, 0, stream>>>(src, dst, degi, dego);
    k_invdeg<<<(NN + 255) / 256, 256, 0, stream>>>(degi, dego);

    // C1 = node_embs @ Bt1[:,0:192]
    gemm64<<<dim3(313, 3), 256, 0, stream>>>(node_embs, NN, 256, 256, Bt1, 256,
                                             C1, 192, 0, nullptr, nullptr, nullptr, nullptr);
    // E1 = edge_embs @ Bt1[:,0:256]
    gemm64<<<dim3(8, 4), 256, 0, stream>>>(edge_embs, NR, 256, 256, Bt1, 256,
                                           E1, 256, 0, nullptr, nullptr, nullptr, nullptr);
    k_er1<<<(NR * 64 + 255) / 256, 256, 0, stream>>>(E1, br1);

    // layer-1 aggregation into agg1
    k_agg<<<NE / 4, 256, 0, stream>>>(src, dst, evid,
                                      C1, 192, 0, 64,
                                      E1, 256, 0, 64,
                                      degi, dego,
                                      agg1, 128, 0, 64);
    k_combine1<<<(NN * 64 + 255) / 256, 256, 0, stream>>>(agg1, C1, s1, t1, A2);

    // layer-2 aggregation into A2 cols [0,128)
    k_agg<<<NE / 4, 256, 0, stream>>>(src, dst, evid,
                                      A2, 192, 128, 128,
                                      E1, 256, 192, 192,
                                      degi, dego,
                                      A2, 192, 0, 64);

    // hn = tanh((A2 @ Bt2) * s2 + t2)  (or node_embs if !upd)
    gemm64<<<dim3(313, 4), 256, 0, stream>>>(A2, NN, 192, 192, Bt2, 256,
                                             hn, 256, 2, s2, t2, node_embs, upd);

    k_rels<<<BQ, 64, 0, stream>>>(edge_embs, Wr1, br1, Wr2, br2,
                                  hids, rids, tids, ihead, hn, tvec);
    k_score<<<(BQ * (NN / BQ)) / 4, 256, 0, stream>>>(hn, tvec, score);
}

// Round 2
// 396.933 us; speedup vs baseline: 1.2008x; 1.2008x over previous
//
#include <hip/hip_runtime.h>
#include <math.h>

#define NN 20000     // nodes
#define NE 320000    // edges
#define NR 500       // relations
#define EMBD 256
#define D4 64
#define BQ 32        // batch

// ---------------- small param kernels ----------------

__global__ void k_params(const float* __restrict__ bO1, const float* __restrict__ bI1,
                         const float* __restrict__ bS1,
                         const float* __restrict__ g1, const float* __restrict__ bb1,
                         const float* __restrict__ m1, const float* __restrict__ v1,
                         const float* __restrict__ bO2, const float* __restrict__ bI2,
                         const float* __restrict__ bS2,
                         const float* __restrict__ g2, const float* __restrict__ bb2,
                         const float* __restrict__ m2, const float* __restrict__ v2,
                         float* __restrict__ s1, float* __restrict__ t1,
                         float* __restrict__ s2, float* __restrict__ t2)
{
    int i = blockIdx.x * 256 + threadIdx.x;
    if (i < 64) {
        float rsg = g1[i] / sqrtf(v1[i] + 1e-5f);
        s1[i] = rsg * (1.f / 3.f);
        t1[i] = ((bO1[i] + bI1[i] + bS1[i]) * (1.f / 3.f) - m1[i]) * rsg + bb1[i];
    } else if (i < 64 + 256) {
        int n = i - 64;
        float rsg = g2[n] / sqrtf(v2[n] + 1e-5f);
        s2[n] = rsg * (1.f / 3.f);
        t2[n] = ((bO2[n] + bI2[n] + bS2[n]) * (1.f / 3.f) - m2[n]) * rsg + bb2[n];
    }
}

// Build k-major weight blocks:
// Bt1[k][n], 256x256: n<64 W_O1[n][k]; <128 W_I1; <192 W_S1; <256 Wr1
// Bt2[k][n], 192x256: k<64 W_O2[n][k]; <128 W_I2[n][k-64]; <192 W_S2[n][k-128]
__global__ void k_buildBt(const float* __restrict__ W_O1, const float* __restrict__ W_I1,
                          const float* __restrict__ W_S1, const float* __restrict__ Wr1,
                          const float* __restrict__ W_O2, const float* __restrict__ W_I2,
                          const float* __restrict__ W_S2,
                          float* __restrict__ Bt1, float* __restrict__ Bt2)
{
    int id = blockIdx.x * 256 + threadIdx.x;
    if (id < 256 * 256) {
        int k = id >> 8, n = id & 255;
        float v;
        if (n < 64)       v = W_O1[n * 256 + k];
        else if (n < 128) v = W_I1[(n - 64) * 256 + k];
        else if (n < 192) v = W_S1[(n - 128) * 256 + k];
        else              v = Wr1[(n - 192) * 256 + k];
        Bt1[id] = v;
    } else {
        int id2 = id - 256 * 256;
        if (id2 < 192 * 256) {
            int k = id2 >> 8, n = id2 & 255;
            float v;
            if (k < 64)       v = W_O2[n * 64 + k];
            else if (k < 128) v = W_I2[n * 64 + (k - 64)];
            else              v = W_S2[n * 64 + (k - 128)];
            Bt2[id2] = v;
        }
    }
}

// ---------------- CSR build ----------------

__global__ void k_hist(const int* __restrict__ src, const int* __restrict__ dst,
                       int* __restrict__ cnt_in, int* __restrict__ cnt_out)
{
    int i = blockIdx.x * 256 + threadIdx.x;
    if (i < NE) {
        atomicAdd(&cnt_in[dst[i]], 1);
        atomicAdd(&cnt_out[src[i]], 1);
    }
}

__global__ void k_invdeg(const int* __restrict__ cnt_in, const int* __restrict__ cnt_out,
                         float* __restrict__ degi, float* __restrict__ dego)
{
    int n = blockIdx.x * 256 + threadIdx.x;
    if (n < NN) {
        degi[n] = 1.f / fmaxf((float)cnt_in[n], 1.f);
        dego[n] = 1.f / fmaxf((float)cnt_out[n], 1.f);
    }
}

// single-block exclusive scan (1024 threads, chunk=20) for both count arrays;
// writes off[] (NN+1) and initializes cur[] = off[]
__global__ __launch_bounds__(1024) void k_scan(
    const int* __restrict__ cnt_in, int* __restrict__ off_in, int* __restrict__ cur_in,
    const int* __restrict__ cnt_out, int* __restrict__ off_out, int* __restrict__ cur_out)
{
    __shared__ int lds[1024];
    const int t = threadIdx.x;
    const int CH = 20;
    for (int pass = 0; pass < 2; ++pass) {
        const int* cnt = pass ? cnt_out : cnt_in;
        int* off = pass ? off_out : off_in;
        int* cur = pass ? cur_out : cur_in;
        int s = 0;
        for (int c = 0; c < CH; ++c) {
            int idx = t * CH + c;
            if (idx < NN) s += cnt[idx];
        }
        lds[t] = s;
        __syncthreads();
        for (int d = 1; d < 1024; d <<= 1) {
            int v = (t >= d) ? lds[t - d] : 0;
            __syncthreads();
            lds[t] += v;
            __syncthreads();
        }
        int run = (t > 0) ? lds[t - 1] : 0;
        if (t == 1023) off[NN] = lds[1023];
        for (int c = 0; c < CH; ++c) {
            int idx = t * CH + c;
            if (idx < NN) {
                off[idx] = run;
                cur[idx] = run;
                run += cnt[idx];
            }
        }
        __syncthreads();
    }
}

// scatter packed edge records: ein[p]={src,evid} grouped by dst; eout[p]={dst,evid} by src
__global__ void k_scatter(const int* __restrict__ src, const int* __restrict__ dst,
                          const int* __restrict__ evid,
                          int* __restrict__ cur_in, int* __restrict__ cur_out,
                          int2* __restrict__ ein, int2* __restrict__ eout)
{
    int e = blockIdx.x * 256 + threadIdx.x;
    if (e >= NE) return;
    int s = src[e], d = dst[e], r = evid[e];
    int p = atomicAdd(&cur_in[d], 1);
    ein[p] = make_int2(s, r);
    int q = atomicAdd(&cur_out[s], 1);
    eout[q] = make_int2(d, r);
}

// er1 = tanh(raw + br1), in place on E1 cols [192,256)
__global__ void k_er1(float* __restrict__ E1, const float* __restrict__ br1)
{
    int id = blockIdx.x * 256 + threadIdx.x;
    if (id >= NR * 64) return;
    int r = id >> 6, j = id & 63;
    float v = E1[r * 256 + 192 + j];
    E1[r * 256 + 192 + j] = tanhf(v + br1[j]);
}

// ---------------- tiled f32 GEMM: C = A @ Bt  (Bt is [K][N] k-major) ----------------
// mode 0: raw store to C (ldc). mode 2: hn epilogue tanh(acc*sv[n]+tv[n]) (or node_embs if !flag)
__global__ __launch_bounds__(256) void gemm64(
    const float* __restrict__ A, int M, int K, int lda,
    const float* __restrict__ Bt, int ldb,
    float* __restrict__ C, int ldc, int mode,
    const float* __restrict__ sv, const float* __restrict__ tv,
    const float* __restrict__ node_embs, const int* __restrict__ flag)
{
    __shared__ float As[64][68];   // k-major: As[k][m]
    __shared__ float Bs[64][68];   // Bs[k][n]
    const int t = threadIdx.x;
    const int m0 = blockIdx.x * 64, n0 = blockIdx.y * 64;
    const int tn = t & 15, to = t >> 4;
    float acc[4][4] = {};

    for (int kb = 0; kb < K; kb += 64) {
#pragma unroll
        for (int it = 0; it < 4; ++it) {
            int idx = t + it * 256;          // [0,1024)
            int kq = idx & 15;               // k-quad
            int m = idx >> 4;                // row (A) / k (B)
            int gm = m0 + m;
            float4 a = make_float4(0.f, 0.f, 0.f, 0.f);
            if (gm < M) a = *(const float4*)(A + (size_t)gm * lda + kb + 4 * kq);
            As[4 * kq + 0][m] = a.x;
            As[4 * kq + 1][m] = a.y;
            As[4 * kq + 2][m] = a.z;
            As[4 * kq + 3][m] = a.w;
            float4 b = *(const float4*)(Bt + (size_t)(kb + m) * ldb + n0 + 4 * kq);
            *(float4*)&Bs[m][4 * kq] = b;
        }
        __syncthreads();
#pragma unroll 8
        for (int kk = 0; kk < 64; ++kk) {
            float4 av = *(const float4*)&As[kk][4 * tn];
            float4 bv = *(const float4*)&Bs[kk][4 * to];
            float a0 = av.x, a1 = av.y, a2 = av.z, a3 = av.w;
            float b0 = bv.x, b1 = bv.y, b2 = bv.z, b3 = bv.w;
            acc[0][0] = fmaf(a0, b0, acc[0][0]); acc[0][1] = fmaf(a0, b1, acc[0][1]);
            acc[0][2] = fmaf(a0, b2, acc[0][2]); acc[0][3] = fmaf(a0, b3, acc[0][3]);
            acc[1][0] = fmaf(a1, b0, acc[1][0]); acc[1][1] = fmaf(a1, b1, acc[1][1]);
            acc[1][2] = fmaf(a1, b2, acc[1][2]); acc[1][3] = fmaf(a1, b3, acc[1][3]);
            acc[2][0] = fmaf(a2, b0, acc[2][0]); acc[2][1] = fmaf(a2, b1, acc[2][1]);
            acc[2][2] = fmaf(a2, b2, acc[2][2]); acc[2][3] = fmaf(a2, b3, acc[2][3]);
            acc[3][0] = fmaf(a3, b0, acc[3][0]); acc[3][1] = fmaf(a3, b1, acc[3][1]);
            acc[3][2] = fmaf(a3, b2, acc[3][2]); acc[3][3] = fmaf(a3, b3, acc[3][3]);
        }
        __syncthreads();
    }

#pragma unroll
    for (int i = 0; i < 4; ++i) {
        int gm = m0 + 4 * tn + i;
        if (gm >= M) continue;
#pragma unroll
        for (int j = 0; j < 4; ++j) {
            int gn = n0 + 4 * to + j;
            float v = acc[i][j];
            if (mode == 0) {
                C[(size_t)gm * ldc + gn] = v;
            } else {
                float val = tanhf(v * sv[gn] + tv[gn]);
                if (flag[0] == 0) val = node_embs[(size_t)gm * EMBD + gn];
                C[(size_t)gm * EMBD + gn] = val;
            }
        }
    }
}

// ---------------- CSR gather aggregation: one wave per node, lane = dim ----------------
// layer 1 fused with combine: h1 = tanh((accO/degi + accI/dego + hS1raw)*s1 + t1)
__global__ __launch_bounds__(256) void k_gather1(
    const int* __restrict__ off_in, const int* __restrict__ off_out,
    const int2* __restrict__ ein, const int2* __restrict__ eout,
    const float* __restrict__ C1, const float* __restrict__ E1,
    const float* __restrict__ invdegi, const float* __restrict__ invdego,
    const float* __restrict__ s1, const float* __restrict__ t1,
    float* __restrict__ A2)
{
    int n = blockIdx.x * 4 + (threadIdx.x >> 6);
    if (n >= NN) return;
    int j = threadIdx.x & 63;
    float accO = 0.f;
    int b0 = off_in[n], b1 = off_in[n + 1];
    for (int i = b0; i < b1; ++i) {
        int2 er = ein[i];
        accO += C1[(size_t)er.x * 192 + j] - E1[(size_t)er.y * 256 + j];
    }
    float accI = 0.f;
    int c0 = off_out[n], c1 = off_out[n + 1];
    for (int i = c0; i < c1; ++i) {
        int2 er = eout[i];
        accI += C1[(size_t)er.x * 192 + 64 + j] - E1[(size_t)er.y * 256 + 64 + j];
    }
    float x = accO * invdegi[n] + accI * invdego[n] + C1[(size_t)n * 192 + 128 + j];
    A2[(size_t)n * 192 + 128 + j] = tanhf(x * s1[j] + t1[j]);
}

// layer 2: aggregate h1 (A2 cols[128,192)) minus er1 (E1 cols[192,256)); write A2 cols [0,128)
__global__ __launch_bounds__(256) void k_gather2(
    const int* __restrict__ off_in, const int* __restrict__ off_out,
    const int2* __restrict__ ein, const int2* __restrict__ eout,
    const float* __restrict__ A2r, const float* __restrict__ E1,
    const float* __restrict__ invdegi, const float* __restrict__ invdego,
    float* __restrict__ A2w)
{
    int n = blockIdx.x * 4 + (threadIdx.x >> 6);
    if (n >= NN) return;
    int j = threadIdx.x & 63;
    float accO = 0.f;
    int b0 = off_in[n], b1 = off_in[n + 1];
    for (int i = b0; i < b1; ++i) {
        int2 er = ein[i];
        accO += A2r[(size_t)er.x * 192 + 128 + j] - E1[(size_t)er.y * 256 + 192 + j];
    }
    float accI = 0.f;
    int c0 = off_out[n], c1 = off_out[n + 1];
    for (int i = c0; i < c1; ++i) {
        int2 er = eout[i];
        accI += A2r[(size_t)er.x * 192 + 128 + j] - E1[(size_t)er.y * 256 + 192 + j];
    }
    A2w[(size_t)n * 192 + j]      = accO * invdegi[n];
    A2w[(size_t)n * 192 + 64 + j] = accI * invdego[n];
}

// ---------------- scoring ----------------
__global__ __launch_bounds__(64) void k_rels(
    const float* __restrict__ edge_embs,
    const float* __restrict__ Wr1, const float* __restrict__ br1,
    const float* __restrict__ Wr2, const float* __restrict__ br2,
    const int* __restrict__ hids, const int* __restrict__ rids, const int* __restrict__ tids,
    const int* __restrict__ is_head, const float* __restrict__ hn,
    float* __restrict__ tvec)
{
    __shared__ float e_s[256];
    __shared__ float m_s[64];
    int b = blockIdx.x, o = threadIdx.x;
    int rid = rids[b];
#pragma unroll
    for (int q = 0; q < 4; ++q) e_s[o + 64 * q] = edge_embs[(size_t)rid * 256 + o + 64 * q];
    __syncthreads();
    float acc = br1[o];
    for (int k = 0; k < 256; ++k) acc = fmaf(e_s[k], Wr1[o * 256 + k], acc);
    m_s[o] = fmaxf(acc, 0.f);
    __syncthreads();
    int ih = is_head[0];
    int nid = ih ? tids[b] : hids[b];
#pragma unroll
    for (int q = 0; q < 4; ++q) {
        int n = o + 64 * q;
        float r = br2[n];
        for (int jj = 0; jj < 64; ++jj) r = fmaf(m_s[jj], Wr2[n * 64 + jj], r);
        float hv = hn[(size_t)nid * 256 + n];
        tvec[b * 256 + n] = ih ? (hv - r) : (hv + r);
    }
}

__global__ __launch_bounds__(256) void k_score(
    const float* __restrict__ hn, const float* __restrict__ tvec,
    float* __restrict__ score)
{
    int p = blockIdx.x * 4 + (threadIdx.x >> 6);
    if (p >= BQ * (NN / BQ)) return;
    int l = threadIdx.x & 63;
    int b = p / (NN / BQ);
    int j = p - b * (NN / BQ);
    int idx = (b * NN + 32 * j) / BQ;   // faithful repeat_interleave indexing
    float ssum = 0.f;
#pragma unroll
    for (int q = 0; q < 4; ++q) {
        float df = hn[(size_t)idx * 256 + l + 64 * q] - tvec[b * 256 + l + 64 * q];
        ssum = fmaf(df, df, ssum);
    }
#pragma unroll
    for (int off = 32; off >= 1; off >>= 1) ssum += __shfl_xor(ssum, off, 64);
    float dist = sqrtf(ssum);
    float sc = 1.f / (1.f + expf(dist - 12.f));
    if (l < 32) score[(size_t)b * NN + 32 * j + l] = sc;
}

// ---------------- launch ----------------
extern "C" void kernel_launch(void* const* d_in, const int* in_sizes, int n_in,
                              void* d_out, int out_size, void* d_ws, size_t ws_size,
                              hipStream_t stream)
{
    const float* node_embs = (const float*)d_in[0];
    const float* edge_embs = (const float*)d_in[1];
    const float* W_O1 = (const float*)d_in[2];  const float* b_O1 = (const float*)d_in[3];
    const float* W_I1 = (const float*)d_in[4];  const float* b_I1 = (const float*)d_in[5];
    const float* W_S1 = (const float*)d_in[6];  const float* b_S1 = (const float*)d_in[7];
    const float* bn1_g = (const float*)d_in[8]; const float* bn1_b = (const float*)d_in[9];
    const float* bn1_m = (const float*)d_in[10];const float* bn1_v = (const float*)d_in[11];
    const float* Wr1 = (const float*)d_in[12];  const float* br1 = (const float*)d_in[13];
    const float* W_O2 = (const float*)d_in[14]; const float* b_O2 = (const float*)d_in[15];
    const float* W_I2 = (const float*)d_in[16]; const float* b_I2 = (const float*)d_in[17];
    const float* W_S2 = (const float*)d_in[18]; const float* b_S2 = (const float*)d_in[19];
    const float* bn2_g = (const float*)d_in[20];const float* bn2_b = (const float*)d_in[21];
    const float* bn2_m = (const float*)d_in[22];const float* bn2_v = (const float*)d_in[23];
    const float* Wr2 = (const float*)d_in[24];  const float* br2 = (const float*)d_in[25];
    const int* src = (const int*)d_in[26];
    const int* dst = (const int*)d_in[27];
    const int* evid = (const int*)d_in[28];
    const int* hids = (const int*)d_in[29];
    const int* rids = (const int*)d_in[30];
    const int* tids = (const int*)d_in[31];
    const int* upd = (const int*)d_in[32];
    const int* ihead = (const int*)d_in[33];

    float* ws = (float*)d_ws;
    float* C1   = ws;                      // 20000*192  : [hO1 | hI1 | hS1raw]
    float* A2   = C1 + 3840000;            // 20000*192  : [agg2O' | agg2I' | h1]
    float* E1   = A2 + 3840000;            // 500*256    : [eO1 | eI1 | (unused) | er1]
    float* Bt1  = E1 + 128000;             // 256*256
    float* Bt2  = Bt1 + 65536;             // 192*256
    float* degi = Bt2 + 49152;             // 20000 (invdeg_in)
    float* dego = degi + 20000;            // 20000 (invdeg_out)
    float* s1   = dego + 20000;            // 64
    float* t1   = s1 + 64;                 // 64
    float* s2   = t1 + 64;                 // 256
    float* t2   = s2 + 256;                // 256
    float* tvec = t2 + 256;                // 32*256

    int2* ein   = (int2*)(tvec + 8192);    // NE int2 (8B-aligned: all prior offsets even)
    int2* eout  = ein + NE;                // NE int2
    int* cnt_in = (int*)(eout + NE);       // NN
    int* cnt_out= cnt_in + NN;             // NN
    int* off_in = cnt_out + NN;            // NN+1
    int* off_out= off_in + NN + 1;         // NN+1
    int* cur_in = off_out + NN + 1;        // NN
    int* cur_out= cur_in + NN;             // NN

    float* hn    = (float*)d_out;                       // 20000*256
    float* score = hn + (size_t)NN * EMBD;              // 32*20000

    hipMemsetAsync(cnt_in, 0, (size_t)2 * NN * 4, stream);

    k_params<<<2, 256, 0, stream>>>(b_O1, b_I1, b_S1, bn1_g, bn1_b, bn1_m, bn1_v,
                                    b_O2, b_I2, b_S2, bn2_g, bn2_b, bn2_m, bn2_v,
                                    s1, t1, s2, t2);
    k_buildBt<<<(256 * 256 + 192 * 256 + 255) / 256, 256, 0, stream>>>(
        W_O1, W_I1, W_S1, Wr1, W_O2, W_I2, W_S2, Bt1, Bt2);

    // CSR build
    k_hist<<<(NE + 255) / 256, 256, 0, stream>>>(src, dst, cnt_in, cnt_out);
    k_invdeg<<<(NN + 255) / 256, 256, 0, stream>>>(cnt_in, cnt_out, degi, dego);
    k_scan<<<1, 1024, 0, stream>>>(cnt_in, off_in, cur_in, cnt_out, off_out, cur_out);
    k_scatter<<<(NE + 255) / 256, 256, 0, stream>>>(src, dst, evid, cur_in, cur_out, ein, eout);

    // C1 = node_embs @ Bt1[:,0:192]
    gemm64<<<dim3(313, 3), 256, 0, stream>>>(node_embs, NN, 256, 256, Bt1, 256,
                                             C1, 192, 0, nullptr, nullptr, nullptr, nullptr);
    // E1 = edge_embs @ Bt1[:,0:256]
    gemm64<<<dim3(8, 4), 256, 0, stream>>>(edge_embs, NR, 256, 256, Bt1, 256,
                                           E1, 256, 0, nullptr, nullptr, nullptr, nullptr);
    k_er1<<<(NR * 64 + 255) / 256, 256, 0, stream>>>(E1, br1);

    // layer-1 aggregation + combine (writes h1 into A2 cols [128,192))
    k_gather1<<<NN / 4, 256, 0, stream>>>(off_in, off_out, ein, eout, C1, E1,
                                          degi, dego, s1, t1, A2);
    // layer-2 aggregation (writes A2 cols [0,128))
    k_gather2<<<NN / 4, 256, 0, stream>>>(off_in, off_out, ein, eout, A2, E1,
                                          degi, dego, A2);

    // hn = tanh((A2 @ Bt2) * s2 + t2)  (or node_embs if !upd)
    gemm64<<<dim3(313, 4), 256, 0, stream>>>(A2, NN, 192, 192, Bt2, 256,
                                             hn, 256, 2, s2, t2, node_embs, upd);

    k_rels<<<BQ, 64, 0, stream>>>(edge_embs, Wr1, br1, Wr2, br2,
                                  hids, rids, tids, ihead, hn, tvec);
    k_score<<<(BQ * (NN / BQ)) / 4, 256, 0, stream>>>(hn, tvec, score);
}

// Round 3
// 337.240 us; speedup vs baseline: 1.4133x; 1.1770x over previous
//
#include <hip/hip_runtime.h>
#include <math.h>

#define NN 20000     // nodes
#define NE 320000    // edges
#define NR 500       // relations
#define EMBD 256
#define D4 64
#define BQ 32        // batch
#define TOT (2 * NN) // concatenated count length
#define NB 40        // scan blocks (40*1024 >= TOT)

// ---------------- small param kernels ----------------

__global__ void k_params(const float* __restrict__ bO1, const float* __restrict__ bI1,
                         const float* __restrict__ bS1,
                         const float* __restrict__ g1, const float* __restrict__ bb1,
                         const float* __restrict__ m1, const float* __restrict__ v1,
                         const float* __restrict__ bO2, const float* __restrict__ bI2,
                         const float* __restrict__ bS2,
                         const float* __restrict__ g2, const float* __restrict__ bb2,
                         const float* __restrict__ m2, const float* __restrict__ v2,
                         float* __restrict__ s1, float* __restrict__ t1,
                         float* __restrict__ s2, float* __restrict__ t2)
{
    int i = blockIdx.x * 256 + threadIdx.x;
    if (i < 64) {
        float rsg = g1[i] / sqrtf(v1[i] + 1e-5f);
        s1[i] = rsg * (1.f / 3.f);
        t1[i] = ((bO1[i] + bI1[i] + bS1[i]) * (1.f / 3.f) - m1[i]) * rsg + bb1[i];
    } else if (i < 64 + 256) {
        int n = i - 64;
        float rsg = g2[n] / sqrtf(v2[n] + 1e-5f);
        s2[n] = rsg * (1.f / 3.f);
        t2[n] = ((bO2[n] + bI2[n] + bS2[n]) * (1.f / 3.f) - m2[n]) * rsg + bb2[n];
    }
}

// Build k-major weight blocks:
// Bt1[k][n], 256x256: n<64 W_O1[n][k]; <128 W_I1; <192 W_S1; <256 Wr1
// Bt2[k][n], 192x256: k<64 W_O2[n][k]; <128 W_I2[n][k-64]; <192 W_S2[n][k-128]
__global__ void k_buildBt(const float* __restrict__ W_O1, const float* __restrict__ W_I1,
                          const float* __restrict__ W_S1, const float* __restrict__ Wr1,
                          const float* __restrict__ W_O2, const float* __restrict__ W_I2,
                          const float* __restrict__ W_S2,
                          float* __restrict__ Bt1, float* __restrict__ Bt2)
{
    int id = blockIdx.x * 256 + threadIdx.x;
    if (id < 256 * 256) {
        int k = id >> 8, n = id & 255;
        float v;
        if (n < 64)       v = W_O1[n * 256 + k];
        else if (n < 128) v = W_I1[(n - 64) * 256 + k];
        else if (n < 192) v = W_S1[(n - 128) * 256 + k];
        else              v = Wr1[(n - 192) * 256 + k];
        Bt1[id] = v;
    } else {
        int id2 = id - 256 * 256;
        if (id2 < 192 * 256) {
            int k = id2 >> 8, n = id2 & 255;
            float v;
            if (k < 64)       v = W_O2[n * 64 + k];
            else if (k < 128) v = W_I2[n * 64 + (k - 64)];
            else              v = W_S2[n * 64 + (k - 128)];
            Bt2[id2] = v;
        }
    }
}

// ---------------- CSR build ----------------

// cnt = [cnt_in | cnt_out] concatenated (length 2*NN)
__global__ void k_hist(const int* __restrict__ src, const int* __restrict__ dst,
                       int* __restrict__ cnt)
{
    int i = blockIdx.x * 256 + threadIdx.x;
    if (i < NE) {
        atomicAdd(&cnt[dst[i]], 1);
        atomicAdd(&cnt[NN + src[i]], 1);
    }
}

__global__ void k_invdeg(const int* __restrict__ cnt,
                         float* __restrict__ degi, float* __restrict__ dego)
{
    int n = blockIdx.x * 256 + threadIdx.x;
    if (n < NN) {
        degi[n] = 1.f / fmaxf((float)cnt[n], 1.f);
        dego[n] = 1.f / fmaxf((float)cnt[NN + n], 1.f);
    }
}

// phase A: per-block (1024 elems) sum -> bsum
__global__ __launch_bounds__(256) void k_scanA(const int* __restrict__ cnt,
                                               int* __restrict__ bsum)
{
    __shared__ int lds[256];
    int t = threadIdx.x;
    int base = blockIdx.x * 1024 + t * 4;
    int s = 0;
    if (base + 3 < TOT) {
        int4 v = *(const int4*)(cnt + base);
        s = v.x + v.y + v.z + v.w;
    } else {
        for (int c = 0; c < 4; ++c) { int i = base + c; if (i < TOT) s += cnt[i]; }
    }
    lds[t] = s;
    __syncthreads();
    for (int d = 128; d > 0; d >>= 1) {
        if (t < d) lds[t] += lds[t + d];
        __syncthreads();
    }
    if (t == 0) bsum[blockIdx.x] = lds[0];
}

// phase B: one wave exclusive-scans NB block sums in place
__global__ __launch_bounds__(64) void k_scanB(int* __restrict__ bsum)
{
    int t = threadIdx.x;
    int v = (t < NB) ? bsum[t] : 0;
#pragma unroll
    for (int d = 1; d < 64; d <<= 1) {
        int u = __shfl_up(v, d, 64);
        if (t >= d) v += u;
    }
    int ex = __shfl_up(v, 1, 64);
    if (t == 0) ex = 0;
    if (t < NB) bsum[t] = ex;
}

// phase C: local exclusive scan + block offset -> offc, cur
__global__ __launch_bounds__(256) void k_scanC(const int* __restrict__ cnt,
                                               const int* __restrict__ bsum,
                                               int* __restrict__ offc,
                                               int* __restrict__ cur)
{
    __shared__ int lds[256];
    int t = threadIdx.x;
    int base = blockIdx.x * 1024 + t * 4;
    int e0 = 0, e1 = 0, e2 = 0, e3 = 0;
    if (base + 3 < TOT) {
        int4 v = *(const int4*)(cnt + base);
        e0 = v.x; e1 = v.y; e2 = v.z; e3 = v.w;
    } else {
        if (base + 0 < TOT) e0 = cnt[base + 0];
        if (base + 1 < TOT) e1 = cnt[base + 1];
        if (base + 2 < TOT) e2 = cnt[base + 2];
        if (base + 3 < TOT) e3 = cnt[base + 3];
    }
    int s = e0 + e1 + e2 + e3;
    lds[t] = s;
    __syncthreads();
    for (int d = 1; d < 256; d <<= 1) {
        int u = (t >= d) ? lds[t - d] : 0;
        __syncthreads();
        lds[t] += u;
        __syncthreads();
    }
    int run = lds[t] - s + bsum[blockIdx.x];
    if (base + 3 < TOT) {
        int4 o = make_int4(run, run + e0, run + e0 + e1, run + e0 + e1 + e2);
        *(int4*)(offc + base) = o;
        *(int4*)(cur + base) = o;
    } else {
        int r = run;
        if (base + 0 < TOT) { offc[base + 0] = r; cur[base + 0] = r; r += e0; }
        if (base + 1 < TOT) { offc[base + 1] = r; cur[base + 1] = r; r += e1; }
        if (base + 2 < TOT) { offc[base + 2] = r; cur[base + 2] = r; r += e2; }
        if (base + 3 < TOT) { offc[base + 3] = r; cur[base + 3] = r; r += e3; }
    }
    if (blockIdx.x == 0 && t == 0) offc[TOT] = 2 * NE;   // grand total is fixed
}

// scatter packed edge records into combined R: in-records [0,NE), out-records [NE,2NE)
__global__ void k_scatter(const int* __restrict__ src, const int* __restrict__ dst,
                          const int* __restrict__ evid,
                          int* __restrict__ cur, int2* __restrict__ R)
{
    int e = blockIdx.x * 256 + threadIdx.x;
    if (e >= NE) return;
    int s = src[e], d = dst[e], r = evid[e];
    int p = atomicAdd(&cur[d], 1);
    R[p] = make_int2(s, r);
    int q = atomicAdd(&cur[NN + s], 1);
    R[q] = make_int2(d, r);
}

// er1 = tanh(raw + br1), in place on E1 cols [192,256)
__global__ void k_er1(float* __restrict__ E1, const float* __restrict__ br1)
{
    int id = blockIdx.x * 256 + threadIdx.x;
    if (id >= NR * 64) return;
    int r = id >> 6, j = id & 63;
    float v = E1[r * 256 + 192 + j];
    E1[r * 256 + 192 + j] = tanhf(v + br1[j]);
}

// ---------------- tiled f32 GEMM: C = A @ Bt  (Bt is [K][N] k-major) ----------------
// mode 0: raw store to C (ldc). mode 2: hn epilogue tanh(acc*sv[n]+tv[n]) (or node_embs if !flag)
__global__ __launch_bounds__(256) void gemm64(
    const float* __restrict__ A, int M, int K, int lda,
    const float* __restrict__ Bt, int ldb,
    float* __restrict__ C, int ldc, int mode,
    const float* __restrict__ sv, const float* __restrict__ tv,
    const float* __restrict__ node_embs, const int* __restrict__ flag)
{
    __shared__ float As[64][68];   // k-major: As[k][m]
    __shared__ float Bs[64][68];   // Bs[k][n]
    const int t = threadIdx.x;
    const int m0 = blockIdx.x * 64, n0 = blockIdx.y * 64;
    const int tn = t & 15, to = t >> 4;
    float acc[4][4] = {};

    for (int kb = 0; kb < K; kb += 64) {
#pragma unroll
        for (int it = 0; it < 4; ++it) {
            int idx = t + it * 256;          // [0,1024)
            int kq = idx & 15;               // k-quad
            int m = idx >> 4;                // row (A) / k (B)
            int gm = m0 + m;
            float4 a = make_float4(0.f, 0.f, 0.f, 0.f);
            if (gm < M) a = *(const float4*)(A + (size_t)gm * lda + kb + 4 * kq);
            As[4 * kq + 0][m] = a.x;
            As[4 * kq + 1][m] = a.y;
            As[4 * kq + 2][m] = a.z;
            As[4 * kq + 3][m] = a.w;
            float4 b = *(const float4*)(Bt + (size_t)(kb + m) * ldb + n0 + 4 * kq);
            *(float4*)&Bs[m][4 * kq] = b;
        }
        __syncthreads();
#pragma unroll 8
        for (int kk = 0; kk < 64; ++kk) {
            float4 av = *(const float4*)&As[kk][4 * tn];
            float4 bv = *(const float4*)&Bs[kk][4 * to];
            float a0 = av.x, a1 = av.y, a2 = av.z, a3 = av.w;
            float b0 = bv.x, b1 = bv.y, b2 = bv.z, b3 = bv.w;
            acc[0][0] = fmaf(a0, b0, acc[0][0]); acc[0][1] = fmaf(a0, b1, acc[0][1]);
            acc[0][2] = fmaf(a0, b2, acc[0][2]); acc[0][3] = fmaf(a0, b3, acc[0][3]);
            acc[1][0] = fmaf(a1, b0, acc[1][0]); acc[1][1] = fmaf(a1, b1, acc[1][1]);
            acc[1][2] = fmaf(a1, b2, acc[1][2]); acc[1][3] = fmaf(a1, b3, acc[1][3]);
            acc[2][0] = fmaf(a2, b0, acc[2][0]); acc[2][1] = fmaf(a2, b1, acc[2][1]);
            acc[2][2] = fmaf(a2, b2, acc[2][2]); acc[2][3] = fmaf(a2, b3, acc[2][3]);
            acc[3][0] = fmaf(a3, b0, acc[3][0]); acc[3][1] = fmaf(a3, b1, acc[3][1]);
            acc[3][2] = fmaf(a3, b2, acc[3][2]); acc[3][3] = fmaf(a3, b3, acc[3][3]);
        }
        __syncthreads();
    }

#pragma unroll
    for (int i = 0; i < 4; ++i) {
        int gm = m0 + 4 * tn + i;
        if (gm >= M) continue;
#pragma unroll
        for (int j = 0; j < 4; ++j) {
            int gn = n0 + 4 * to + j;
            float v = acc[i][j];
            if (mode == 0) {
                C[(size_t)gm * ldc + gn] = v;
            } else {
                float val = tanhf(v * sv[gn] + tv[gn]);
                if (flag[0] == 0) val = node_embs[(size_t)gm * EMBD + gn];
                C[(size_t)gm * EMBD + gn] = val;
            }
        }
    }
}

// ---------------- CSR gather aggregation: one wave per node, lane = dim ----------------
// layer 1 fused with combine: h1 = tanh((accO/degi + accI/dego + hS1raw)*s1 + t1)
__global__ __launch_bounds__(256) void k_gather1(
    const int* __restrict__ offc, const int2* __restrict__ R,
    const float* __restrict__ C1, const float* __restrict__ E1,
    const float* __restrict__ invdegi, const float* __restrict__ invdego,
    const float* __restrict__ s1, const float* __restrict__ t1,
    float* __restrict__ A2)
{
    int n = blockIdx.x * 4 + (threadIdx.x >> 6);
    if (n >= NN) return;
    int j = threadIdx.x & 63;
    float accO = 0.f;
    int b0 = offc[n], b1 = offc[n + 1];
    for (int i = b0; i < b1; ++i) {
        int2 er = R[i];
        accO += C1[(size_t)er.x * 192 + j] - E1[(size_t)er.y * 256 + j];
    }
    float accI = 0.f;
    int c0 = offc[NN + n], c1 = offc[NN + n + 1];
    for (int i = c0; i < c1; ++i) {
        int2 er = R[i];
        accI += C1[(size_t)er.x * 192 + 64 + j] - E1[(size_t)er.y * 256 + 64 + j];
    }
    float x = accO * invdegi[n] + accI * invdego[n] + C1[(size_t)n * 192 + 128 + j];
    A2[(size_t)n * 192 + 128 + j] = tanhf(x * s1[j] + t1[j]);
}

// layer 2: aggregate h1 (A2 cols[128,192)) minus er1 (E1 cols[192,256)); write A2 cols [0,128)
__global__ __launch_bounds__(256) void k_gather2(
    const int* __restrict__ offc, const int2* __restrict__ R,
    const float* __restrict__ A2r, const float* __restrict__ E1,
    const float* __restrict__ invdegi, const float* __restrict__ invdego,
    float* __restrict__ A2w)
{
    int n = blockIdx.x * 4 + (threadIdx.x >> 6);
    if (n >= NN) return;
    int j = threadIdx.x & 63;
    float accO = 0.f;
    int b0 = offc[n], b1 = offc[n + 1];
    for (int i = b0; i < b1; ++i) {
        int2 er = R[i];
        accO += A2r[(size_t)er.x * 192 + 128 + j] - E1[(size_t)er.y * 256 + 192 + j];
    }
    float accI = 0.f;
    int c0 = offc[NN + n], c1 = offc[NN + n + 1];
    for (int i = c0; i < c1; ++i) {
        int2 er = R[i];
        accI += A2r[(size_t)er.x * 192 + 128 + j] - E1[(size_t)er.y * 256 + 192 + j];
    }
    A2w[(size_t)n * 192 + j]      = accO * invdegi[n];
    A2w[(size_t)n * 192 + 64 + j] = accI * invdego[n];
}

// ---------------- scoring ----------------
__global__ __launch_bounds__(64) void k_rels(
    const float* __restrict__ edge_embs,
    const float* __restrict__ Wr1, const float* __restrict__ br1,
    const float* __restrict__ Wr2, const float* __restrict__ br2,
    const int* __restrict__ hids, const int* __restrict__ rids, const int* __restrict__ tids,
    const int* __restrict__ is_head, const float* __restrict__ hn,
    float* __restrict__ tvec)
{
    __shared__ float e_s[256];
    __shared__ float m_s[64];
    int b = blockIdx.x, o = threadIdx.x;
    int rid = rids[b];
#pragma unroll
    for (int q = 0; q < 4; ++q) e_s[o + 64 * q] = edge_embs[(size_t)rid * 256 + o + 64 * q];
    __syncthreads();
    float acc = br1[o];
    for (int k = 0; k < 256; ++k) acc = fmaf(e_s[k], Wr1[o * 256 + k], acc);
    m_s[o] = fmaxf(acc, 0.f);
    __syncthreads();
    int ih = is_head[0];
    int nid = ih ? tids[b] : hids[b];
#pragma unroll
    for (int q = 0; q < 4; ++q) {
        int n = o + 64 * q;
        float r = br2[n];
        for (int jj = 0; jj < 64; ++jj) r = fmaf(m_s[jj], Wr2[n * 64 + jj], r);
        float hv = hn[(size_t)nid * 256 + n];
        tvec[b * 256 + n] = ih ? (hv - r) : (hv + r);
    }
}

__global__ __launch_bounds__(256) void k_score(
    const float* __restrict__ hn, const float* __restrict__ tvec,
    float* __restrict__ score)
{
    int p = blockIdx.x * 4 + (threadIdx.x >> 6);
    if (p >= BQ * (NN / BQ)) return;
    int l = threadIdx.x & 63;
    int b = p / (NN / BQ);
    int j = p - b * (NN / BQ);
    int idx = (b * NN + 32 * j) / BQ;   // faithful repeat_interleave indexing
    float ssum = 0.f;
#pragma unroll
    for (int q = 0; q < 4; ++q) {
        float df = hn[(size_t)idx * 256 + l + 64 * q] - tvec[b * 256 + l + 64 * q];
        ssum = fmaf(df, df, ssum);
    }
#pragma unroll
    for (int off = 32; off >= 1; off >>= 1) ssum += __shfl_xor(ssum, off, 64);
    float dist = sqrtf(ssum);
    float sc = 1.f / (1.f + expf(dist - 12.f));
    if (l < 32) score[(size_t)b * NN + 32 * j + l] = sc;
}

// ---------------- launch ----------------
extern "C" void kernel_launch(void* const* d_in, const int* in_sizes, int n_in,
                              void* d_out, int out_size, void* d_ws, size_t ws_size,
                              hipStream_t stream)
{
    const float* node_embs = (const float*)d_in[0];
    const float* edge_embs = (const float*)d_in[1];
    const float* W_O1 = (const float*)d_in[2];  const float* b_O1 = (const float*)d_in[3];
    const float* W_I1 = (const float*)d_in[4];  const float* b_I1 = (const float*)d_in[5];
    const float* W_S1 = (const float*)d_in[6];  const float* b_S1 = (const float*)d_in[7];
    const float* bn1_g = (const float*)d_in[8]; const float* bn1_b = (const float*)d_in[9];
    const float* bn1_m = (const float*)d_in[10];const float* bn1_v = (const float*)d_in[11];
    const float* Wr1 = (const float*)d_in[12];  const float* br1 = (const float*)d_in[13];
    const float* W_O2 = (const float*)d_in[14]; const float* b_O2 = (const float*)d_in[15];
    const float* W_I2 = (const float*)d_in[16]; const float* b_I2 = (const float*)d_in[17];
    const float* W_S2 = (const float*)d_in[18]; const float* b_S2 = (const float*)d_in[19];
    const float* bn2_g = (const float*)d_in[20];const float* bn2_b = (const float*)d_in[21];
    const float* bn2_m = (const float*)d_in[22];const float* bn2_v = (const float*)d_in[23];
    const float* Wr2 = (const float*)d_in[24];  const float* br2 = (const float*)d_in[25];
    const int* src = (const int*)d_in[26];
    const int* dst = (const int*)d_in[27];
    const int* evid = (const int*)d_in[28];
    const int* hids = (const int*)d_in[29];
    const int* rids = (const int*)d_in[30];
    const int* tids = (const int*)d_in[31];
    const int* upd = (const int*)d_in[32];
    const int* ihead = (const int*)d_in[33];

    float* ws = (float*)d_ws;
    float* C1   = ws;                      // 20000*192  : [hO1 | hI1 | hS1raw]
    float* A2   = C1 + 3840000;            // 20000*192  : [agg2O' | agg2I' | h1]
    float* E1   = A2 + 3840000;            // 500*256    : [eO1 | eI1 | (unused) | er1]
    float* Bt1  = E1 + 128000;             // 256*256
    float* Bt2  = Bt1 + 65536;             // 192*256
    float* degi = Bt2 + 49152;             // 20000 (invdeg_in)
    float* dego = degi + 20000;            // 20000 (invdeg_out)
    float* s1   = dego + 20000;            // 64
    float* t1   = s1 + 64;                 // 64
    float* s2   = t1 + 64;                 // 256
    float* t2   = s2 + 256;                // 256
    float* tvec = t2 + 256;                // 32*256

    int2* R     = (int2*)(tvec + 8192);    // 2*NE int2 (8B-aligned: prior total is even)
    int* cnt    = (int*)(R + 2 * NE);      // 2*NN
    int* offc   = cnt + 2 * NN;            // 2*NN+1
    int* cur    = offc + 2 * NN + 1;       // 2*NN
    int* bsum   = cur + 2 * NN;            // NB

    float* hn    = (float*)d_out;                       // 20000*256
    float* score = hn + (size_t)NN * EMBD;              // 32*20000

    hipMemsetAsync(cnt, 0, (size_t)2 * NN * 4, stream);

    k_params<<<2, 256, 0, stream>>>(b_O1, b_I1, b_S1, bn1_g, bn1_b, bn1_m, bn1_v,
                                    b_O2, b_I2, b_S2, bn2_g, bn2_b, bn2_m, bn2_v,
                                    s1, t1, s2, t2);
    k_buildBt<<<(256 * 256 + 192 * 256 + 255) / 256, 256, 0, stream>>>(
        W_O1, W_I1, W_S1, Wr1, W_O2, W_I2, W_S2, Bt1, Bt2);

    // CSR build
    k_hist<<<(NE + 255) / 256, 256, 0, stream>>>(src, dst, cnt);
    k_invdeg<<<(NN + 255) / 256, 256, 0, stream>>>(cnt, degi, dego);
    k_scanA<<<NB, 256, 0, stream>>>(cnt, bsum);
    k_scanB<<<1, 64, 0, stream>>>(bsum);
    k_scanC<<<NB, 256, 0, stream>>>(cnt, bsum, offc, cur);
    k_scatter<<<(NE + 255) / 256, 256, 0, stream>>>(src, dst, evid, cur, R);

    // C1 = node_embs @ Bt1[:,0:192]
    gemm64<<<dim3(313, 3), 256, 0, stream>>>(node_embs, NN, 256, 256, Bt1, 256,
                                             C1, 192, 0, nullptr, nullptr, nullptr, nullptr);
    // E1 = edge_embs @ Bt1[:,0:256]
    gemm64<<<dim3(8, 4), 256, 0, stream>>>(edge_embs, NR, 256, 256, Bt1, 256,
                                           E1, 256, 0, nullptr, nullptr, nullptr, nullptr);
    k_er1<<<(NR * 64 + 255) / 256, 256, 0, stream>>>(E1, br1);

    // layer-1 aggregation + combine (writes h1 into A2 cols [128,192))
    k_gather1<<<NN / 4, 256, 0, stream>>>(offc, R, C1, E1, degi, dego, s1, t1, A2);
    // layer-2 aggregation (writes A2 cols [0,128))
    k_gather2<<<NN / 4, 256, 0, stream>>>(offc, R, A2, E1, degi, dego, A2);

    // hn = tanh((A2 @ Bt2) * s2 + t2)  (or node_embs if !upd)
    gemm64<<<dim3(313, 4), 256, 0, stream>>>(A2, NN, 192, 192, Bt2, 256,
                                             hn, 256, 2, s2, t2, node_embs, upd);

    k_rels<<<BQ, 64, 0, stream>>>(edge_embs, Wr1, br1, Wr2, br2,
                                  hids, rids, tids, ihead, hn, tvec);
    k_score<<<(BQ * (NN / BQ)) / 4, 256, 0, stream>>>(hn, tvec, score);
}

// Round 4
// 255.061 us; speedup vs baseline: 1.8687x; 1.3222x over previous
//
#include <hip/hip_runtime.h>
#include <math.h>

#define NN 20000     // nodes
#define NE 320000    // edges
#define NR 500       // relations
#define EMBD 256
#define D4 64
#define BQ 32        // batch
#define TOT (2 * NN) // concatenated count length
#define NB 40        // scan blocks (40*1024 >= TOT)

// ---------------- small param kernels ----------------

__global__ void k_params(const float* __restrict__ bO1, const float* __restrict__ bI1,
                         const float* __restrict__ bS1,
                         const float* __restrict__ g1, const float* __restrict__ bb1,
                         const float* __restrict__ m1, const float* __restrict__ v1,
                         const float* __restrict__ bO2, const float* __restrict__ bI2,
                         const float* __restrict__ bS2,
                         const float* __restrict__ g2, const float* __restrict__ bb2,
                         const float* __restrict__ m2, const float* __restrict__ v2,
                         float* __restrict__ s1, float* __restrict__ t1,
                         float* __restrict__ s2, float* __restrict__ t2)
{
    int i = blockIdx.x * 256 + threadIdx.x;
    if (i < 64) {
        float rsg = g1[i] / sqrtf(v1[i] + 1e-5f);
        s1[i] = rsg * (1.f / 3.f);
        t1[i] = ((bO1[i] + bI1[i] + bS1[i]) * (1.f / 3.f) - m1[i]) * rsg + bb1[i];
    } else if (i < 64 + 256) {
        int n = i - 64;
        float rsg = g2[n] / sqrtf(v2[n] + 1e-5f);
        s2[n] = rsg * (1.f / 3.f);
        t2[n] = ((bO2[n] + bI2[n] + bS2[n]) * (1.f / 3.f) - m2[n]) * rsg + bb2[n];
    }
}

// Build k-major weight blocks:
// Bt1[k][n], 256x256: n<64 W_O1[n][k]; <128 W_I1; <192 W_S1; <256 Wr1
// Bt2[k][n], 192x256: k<64 W_O2[n][k]; <128 W_I2[n][k-64]; <192 W_S2[n][k-128]
__global__ void k_buildBt(const float* __restrict__ W_O1, const float* __restrict__ W_I1,
                          const float* __restrict__ W_S1, const float* __restrict__ Wr1,
                          const float* __restrict__ W_O2, const float* __restrict__ W_I2,
                          const float* __restrict__ W_S2,
                          float* __restrict__ Bt1, float* __restrict__ Bt2)
{
    int id = blockIdx.x * 256 + threadIdx.x;
    if (id < 256 * 256) {
        int k = id >> 8, n = id & 255;
        float v;
        if (n < 64)       v = W_O1[n * 256 + k];
        else if (n < 128) v = W_I1[(n - 64) * 256 + k];
        else if (n < 192) v = W_S1[(n - 128) * 256 + k];
        else              v = Wr1[(n - 192) * 256 + k];
        Bt1[id] = v;
    } else {
        int id2 = id - 256 * 256;
        if (id2 < 192 * 256) {
            int k = id2 >> 8, n = id2 & 255;
            float v;
            if (k < 64)       v = W_O2[n * 64 + k];
            else if (k < 128) v = W_I2[n * 64 + (k - 64)];
            else              v = W_S2[n * 64 + (k - 128)];
            Bt2[id2] = v;
        }
    }
}

// ---------------- CSR build ----------------

// cnt = [cnt_in | cnt_out] concatenated (length 2*NN)
__global__ void k_hist(const int* __restrict__ src, const int* __restrict__ dst,
                       int* __restrict__ cnt)
{
    int i = blockIdx.x * 256 + threadIdx.x;
    if (i < NE) {
        atomicAdd(&cnt[dst[i]], 1);
        atomicAdd(&cnt[NN + src[i]], 1);
    }
}

__global__ void k_invdeg(const int* __restrict__ cnt,
                         float* __restrict__ degi, float* __restrict__ dego)
{
    int n = blockIdx.x * 256 + threadIdx.x;
    if (n < NN) {
        degi[n] = 1.f / fmaxf((float)cnt[n], 1.f);
        dego[n] = 1.f / fmaxf((float)cnt[NN + n], 1.f);
    }
}

// phase A: per-block (1024 elems) sum -> bsum
__global__ __launch_bounds__(256) void k_scanA(const int* __restrict__ cnt,
                                               int* __restrict__ bsum)
{
    __shared__ int lds[256];
    int t = threadIdx.x;
    int base = blockIdx.x * 1024 + t * 4;
    int s = 0;
    if (base + 3 < TOT) {
        int4 v = *(const int4*)(cnt + base);
        s = v.x + v.y + v.z + v.w;
    } else {
        for (int c = 0; c < 4; ++c) { int i = base + c; if (i < TOT) s += cnt[i]; }
    }
    lds[t] = s;
    __syncthreads();
    for (int d = 128; d > 0; d >>= 1) {
        if (t < d) lds[t] += lds[t + d];
        __syncthreads();
    }
    if (t == 0) bsum[blockIdx.x] = lds[0];
}

// phase B: one wave exclusive-scans NB block sums in place
__global__ __launch_bounds__(64) void k_scanB(int* __restrict__ bsum)
{
    int t = threadIdx.x;
    int v = (t < NB) ? bsum[t] : 0;
#pragma unroll
    for (int d = 1; d < 64; d <<= 1) {
        int u = __shfl_up(v, d, 64);
        if (t >= d) v += u;
    }
    int ex = __shfl_up(v, 1, 64);
    if (t == 0) ex = 0;
    if (t < NB) bsum[t] = ex;
}

// phase C: local exclusive scan + block offset -> offc, cur
__global__ __launch_bounds__(256) void k_scanC(const int* __restrict__ cnt,
                                               const int* __restrict__ bsum,
                                               int* __restrict__ offc,
                                               int* __restrict__ cur)
{
    __shared__ int lds[256];
    int t = threadIdx.x;
    int base = blockIdx.x * 1024 + t * 4;
    int e0 = 0, e1 = 0, e2 = 0, e3 = 0;
    if (base + 3 < TOT) {
        int4 v = *(const int4*)(cnt + base);
        e0 = v.x; e1 = v.y; e2 = v.z; e3 = v.w;
    } else {
        if (base + 0 < TOT) e0 = cnt[base + 0];
        if (base + 1 < TOT) e1 = cnt[base + 1];
        if (base + 2 < TOT) e2 = cnt[base + 2];
        if (base + 3 < TOT) e3 = cnt[base + 3];
    }
    int s = e0 + e1 + e2 + e3;
    lds[t] = s;
    __syncthreads();
    for (int d = 1; d < 256; d <<= 1) {
        int u = (t >= d) ? lds[t - d] : 0;
        __syncthreads();
        lds[t] += u;
        __syncthreads();
    }
    int run = lds[t] - s + bsum[blockIdx.x];
    if (base + 3 < TOT) {
        int4 o = make_int4(run, run + e0, run + e0 + e1, run + e0 + e1 + e2);
        *(int4*)(offc + base) = o;
        *(int4*)(cur + base) = o;
    } else {
        int r = run;
        if (base + 0 < TOT) { offc[base + 0] = r; cur[base + 0] = r; r += e0; }
        if (base + 1 < TOT) { offc[base + 1] = r; cur[base + 1] = r; r += e1; }
        if (base + 2 < TOT) { offc[base + 2] = r; cur[base + 2] = r; r += e2; }
        if (base + 3 < TOT) { offc[base + 3] = r; cur[base + 3] = r; r += e3; }
    }
    if (blockIdx.x == 0 && t == 0) offc[TOT] = 2 * NE;   // grand total is fixed
}

// scatter packed edge records into combined R: in-records [0,NE), out-records [NE,2NE)
__global__ void k_scatter(const int* __restrict__ src, const int* __restrict__ dst,
                          const int* __restrict__ evid,
                          int* __restrict__ cur, int2* __restrict__ R)
{
    int e = blockIdx.x * 256 + threadIdx.x;
    if (e >= NE) return;
    int s = src[e], d = dst[e], r = evid[e];
    int p = atomicAdd(&cur[d], 1);
    R[p] = make_int2(s, r);
    int q = atomicAdd(&cur[NN + s], 1);
    R[q] = make_int2(d, r);
}

// er1 = tanh(raw + br1), in place on E1 cols [192,256)
__global__ void k_er1(float* __restrict__ E1, const float* __restrict__ br1)
{
    int id = blockIdx.x * 256 + threadIdx.x;
    if (id >= NR * 64) return;
    int r = id >> 6, j = id & 63;
    float v = E1[r * 256 + 192 + j];
    E1[r * 256 + 192 + j] = tanhf(v + br1[j]);
}

// ---------------- tiled f32 GEMM: C = A @ Bt  (Bt is [K][N] k-major) ----------------
__global__ __launch_bounds__(256) void gemm64(
    const float* __restrict__ A, int M, int K, int lda,
    const float* __restrict__ Bt, int ldb,
    float* __restrict__ C, int ldc, int mode,
    const float* __restrict__ sv, const float* __restrict__ tv,
    const float* __restrict__ node_embs, const int* __restrict__ flag)
{
    __shared__ float As[64][68];   // k-major: As[k][m]
    __shared__ float Bs[64][68];   // Bs[k][n]
    const int t = threadIdx.x;
    const int m0 = blockIdx.x * 64, n0 = blockIdx.y * 64;
    const int tn = t & 15, to = t >> 4;
    float acc[4][4] = {};

    for (int kb = 0; kb < K; kb += 64) {
#pragma unroll
        for (int it = 0; it < 4; ++it) {
            int idx = t + it * 256;          // [0,1024)
            int kq = idx & 15;               // k-quad
            int m = idx >> 4;                // row (A) / k (B)
            int gm = m0 + m;
            float4 a = make_float4(0.f, 0.f, 0.f, 0.f);
            if (gm < M) a = *(const float4*)(A + (size_t)gm * lda + kb + 4 * kq);
            As[4 * kq + 0][m] = a.x;
            As[4 * kq + 1][m] = a.y;
            As[4 * kq + 2][m] = a.z;
            As[4 * kq + 3][m] = a.w;
            float4 b = *(const float4*)(Bt + (size_t)(kb + m) * ldb + n0 + 4 * kq);
            *(float4*)&Bs[m][4 * kq] = b;
        }
        __syncthreads();
#pragma unroll 8
        for (int kk = 0; kk < 64; ++kk) {
            float4 av = *(const float4*)&As[kk][4 * tn];
            float4 bv = *(const float4*)&Bs[kk][4 * to];
            float a0 = av.x, a1 = av.y, a2 = av.z, a3 = av.w;
            float b0 = bv.x, b1 = bv.y, b2 = bv.z, b3 = bv.w;
            acc[0][0] = fmaf(a0, b0, acc[0][0]); acc[0][1] = fmaf(a0, b1, acc[0][1]);
            acc[0][2] = fmaf(a0, b2, acc[0][2]); acc[0][3] = fmaf(a0, b3, acc[0][3]);
            acc[1][0] = fmaf(a1, b0, acc[1][0]); acc[1][1] = fmaf(a1, b1, acc[1][1]);
            acc[1][2] = fmaf(a1, b2, acc[1][2]); acc[1][3] = fmaf(a1, b3, acc[1][3]);
            acc[2][0] = fmaf(a2, b0, acc[2][0]); acc[2][1] = fmaf(a2, b1, acc[2][1]);
            acc[2][2] = fmaf(a2, b2, acc[2][2]); acc[2][3] = fmaf(a2, b3, acc[2][3]);
            acc[3][0] = fmaf(a3, b0, acc[3][0]); acc[3][1] = fmaf(a3, b1, acc[3][1]);
            acc[3][2] = fmaf(a3, b2, acc[3][2]); acc[3][3] = fmaf(a3, b3, acc[3][3]);
        }
        __syncthreads();
    }

#pragma unroll
    for (int i = 0; i < 4; ++i) {
        int gm = m0 + 4 * tn + i;
        if (gm >= M) continue;
#pragma unroll
        for (int j = 0; j < 4; ++j) {
            int gn = n0 + 4 * to + j;
            float v = acc[i][j];
            if (mode == 0) {
                C[(size_t)gm * ldc + gn] = v;
            } else {
                float val = tanhf(v * sv[gn] + tv[gn]);
                if (flag[0] == 0) val = node_embs[(size_t)gm * EMBD + gn];
                C[(size_t)gm * EMBD + gn] = val;
            }
        }
    }
}

// ---------------- CSR gather aggregation, MLP-unrolled ----------------
// Each wave owns one node; lane = dim. Records are staged per-lane (one
// coalesced load per 64 records) and broadcast via shfl; row gathers are
// 4x unrolled so 8 independent 256B loads are in flight per wave.

// accumulate over record range [r0,r1) reading TAB[x*ldt + toff + j] - ETAB[y*256 + eoff + j]
__device__ __forceinline__ float gather_range(
    const int2* __restrict__ R, int r0, int r1, int j,
    const float* __restrict__ TAB, int ldt, int toff,
    const float* __restrict__ ETAB, int eoff)
{
    float acc = 0.f;
    int cnt = r1 - r0;
    for (int base = 0; base < cnt; base += 64) {
        int rem = cnt - base; if (rem > 64) rem = 64;
        int2 myrec = make_int2(0, 0);
        if (j < rem) myrec = R[r0 + base + j];
        int i = 0;
        for (; i + 4 <= rem; i += 4) {
            int x0 = __shfl(myrec.x, i, 64),     y0 = __shfl(myrec.y, i, 64);
            int x1 = __shfl(myrec.x, i + 1, 64), y1 = __shfl(myrec.y, i + 1, 64);
            int x2 = __shfl(myrec.x, i + 2, 64), y2 = __shfl(myrec.y, i + 2, 64);
            int x3 = __shfl(myrec.x, i + 3, 64), y3 = __shfl(myrec.y, i + 3, 64);
            float a0 = TAB[(size_t)x0 * ldt + toff + j];
            float a1 = TAB[(size_t)x1 * ldt + toff + j];
            float a2 = TAB[(size_t)x2 * ldt + toff + j];
            float a3 = TAB[(size_t)x3 * ldt + toff + j];
            float e0 = ETAB[(size_t)y0 * 256 + eoff + j];
            float e1 = ETAB[(size_t)y1 * 256 + eoff + j];
            float e2 = ETAB[(size_t)y2 * 256 + eoff + j];
            float e3 = ETAB[(size_t)y3 * 256 + eoff + j];
            acc += (a0 - e0) + (a1 - e1) + (a2 - e2) + (a3 - e3);
        }
        for (; i < rem; ++i) {
            int x = __shfl(myrec.x, i, 64), y = __shfl(myrec.y, i, 64);
            acc += TAB[(size_t)x * ldt + toff + j] - ETAB[(size_t)y * 256 + eoff + j];
        }
    }
    return acc;
}

// layer 1 fused with combine: h1 = tanh((accO/degi + accI/dego + hS1raw)*s1 + t1)
__global__ __launch_bounds__(256) void k_gather1(
    const int* __restrict__ offc, const int2* __restrict__ R,
    const float* __restrict__ C1, const float* __restrict__ E1,
    const float* __restrict__ invdegi, const float* __restrict__ invdego,
    const float* __restrict__ s1, const float* __restrict__ t1,
    float* __restrict__ A2)
{
    int n = blockIdx.x * 4 + (threadIdx.x >> 6);
    if (n >= NN) return;
    int j = threadIdx.x & 63;
    float accO = gather_range(R, offc[n], offc[n + 1], j, C1, 192, 0, E1, 0);
    float accI = gather_range(R, offc[NN + n], offc[NN + n + 1], j, C1, 192, 64, E1, 64);
    float x = accO * invdegi[n] + accI * invdego[n] + C1[(size_t)n * 192 + 128 + j];
    A2[(size_t)n * 192 + 128 + j] = tanhf(x * s1[j] + t1[j]);
}

// layer 2: aggregate h1 (A2 cols[128,192)) minus er1 (E1 cols[192,256)); write A2 cols [0,128)
__global__ __launch_bounds__(256) void k_gather2(
    const int* __restrict__ offc, const int2* __restrict__ R,
    const float* __restrict__ A2r, const float* __restrict__ E1,
    const float* __restrict__ invdegi, const float* __restrict__ invdego,
    float* __restrict__ A2w)
{
    int n = blockIdx.x * 4 + (threadIdx.x >> 6);
    if (n >= NN) return;
    int j = threadIdx.x & 63;
    float accO = gather_range(R, offc[n], offc[n + 1], j, A2r, 192, 128, E1, 192);
    float accI = gather_range(R, offc[NN + n], offc[NN + n + 1], j, A2r, 192, 128, E1, 192);
    A2w[(size_t)n * 192 + j]      = accO * invdegi[n];
    A2w[(size_t)n * 192 + 64 + j] = accI * invdego[n];
}

// ---------------- scoring ----------------
__global__ __launch_bounds__(64) void k_rels(
    const float* __restrict__ edge_embs,
    const float* __restrict__ Wr1, const float* __restrict__ br1,
    const float* __restrict__ Wr2, const float* __restrict__ br2,
    const int* __restrict__ hids, const int* __restrict__ rids, const int* __restrict__ tids,
    const int* __restrict__ is_head, const float* __restrict__ hn,
    float* __restrict__ tvec)
{
    __shared__ float e_s[256];
    __shared__ float m_s[64];
    int b = blockIdx.x, o = threadIdx.x;
    int rid = rids[b];
#pragma unroll
    for (int q = 0; q < 4; ++q) e_s[o + 64 * q] = edge_embs[(size_t)rid * 256 + o + 64 * q];
    __syncthreads();
    float acc = br1[o];
    for (int k = 0; k < 256; ++k) acc = fmaf(e_s[k], Wr1[o * 256 + k], acc);
    m_s[o] = fmaxf(acc, 0.f);
    __syncthreads();
    int ih = is_head[0];
    int nid = ih ? tids[b] : hids[b];
#pragma unroll
    for (int q = 0; q < 4; ++q) {
        int n = o + 64 * q;
        float r = br2[n];
        for (int jj = 0; jj < 64; ++jj) r = fmaf(m_s[jj], Wr2[n * 64 + jj], r);
        float hv = hn[(size_t)nid * 256 + n];
        tvec[b * 256 + n] = ih ? (hv - r) : (hv + r);
    }
}

__global__ __launch_bounds__(256) void k_score(
    const float* __restrict__ hn, const float* __restrict__ tvec,
    float* __restrict__ score)
{
    int p = blockIdx.x * 4 + (threadIdx.x >> 6);
    if (p >= BQ * (NN / BQ)) return;
    int l = threadIdx.x & 63;
    int b = p / (NN / BQ);
    int j = p - b * (NN / BQ);
    int idx = (b * NN + 32 * j) / BQ;   // faithful repeat_interleave indexing
    float ssum = 0.f;
#pragma unroll
    for (int q = 0; q < 4; ++q) {
        float df = hn[(size_t)idx * 256 + l + 64 * q] - tvec[b * 256 + l + 64 * q];
        ssum = fmaf(df, df, ssum);
    }
#pragma unroll
    for (int off = 32; off >= 1; off >>= 1) ssum += __shfl_xor(ssum, off, 64);
    float dist = sqrtf(ssum);
    float sc = 1.f / (1.f + expf(dist - 12.f));
    if (l < 32) score[(size_t)b * NN + 32 * j + l] = sc;
}

// ---------------- launch ----------------
extern "C" void kernel_launch(void* const* d_in, const int* in_sizes, int n_in,
                              void* d_out, int out_size, void* d_ws, size_t ws_size,
                              hipStream_t stream)
{
    const float* node_embs = (const float*)d_in[0];
    const float* edge_embs = (const float*)d_in[1];
    const float* W_O1 = (const float*)d_in[2];  const float* b_O1 = (const float*)d_in[3];
    const float* W_I1 = (const float*)d_in[4];  const float* b_I1 = (const float*)d_in[5];
    const float* W_S1 = (const float*)d_in[6];  const float* b_S1 = (const float*)d_in[7];
    const float* bn1_g = (const float*)d_in[8]; const float* bn1_b = (const float*)d_in[9];
    const float* bn1_m = (const float*)d_in[10];const float* bn1_v = (const float*)d_in[11];
    const float* Wr1 = (const float*)d_in[12];  const float* br1 = (const float*)d_in[13];
    const float* W_O2 = (const float*)d_in[14]; const float* b_O2 = (const float*)d_in[15];
    const float* W_I2 = (const float*)d_in[16]; const float* b_I2 = (const float*)d_in[17];
    const float* W_S2 = (const float*)d_in[18]; const float* b_S2 = (const float*)d_in[19];
    const float* bn2_g = (const float*)d_in[20];const float* bn2_b = (const float*)d_in[21];
    const float* bn2_m = (const float*)d_in[22];const float* bn2_v = (const float*)d_in[23];
    const float* Wr2 = (const float*)d_in[24];  const float* br2 = (const float*)d_in[25];
    const int* src = (const int*)d_in[26];
    const int* dst = (const int*)d_in[27];
    const int* evid = (const int*)d_in[28];
    const int* hids = (const int*)d_in[29];
    const int* rids = (const int*)d_in[30];
    const int* tids = (const int*)d_in[31];
    const int* upd = (const int*)d_in[32];
    const int* ihead = (const int*)d_in[33];

    float* ws = (float*)d_ws;
    float* C1   = ws;                      // 20000*192  : [hO1 | hI1 | hS1raw]
    float* A2   = C1 + 3840000;            // 20000*192  : [agg2O' | agg2I' | h1]
    float* E1   = A2 + 3840000;            // 500*256    : [eO1 | eI1 | (unused) | er1]
    float* Bt1  = E1 + 128000;             // 256*256
    float* Bt2  = Bt1 + 65536;             // 192*256
    float* degi = Bt2 + 49152;             // 20000 (invdeg_in)
    float* dego = degi + 20000;            // 20000 (invdeg_out)
    float* s1   = dego + 20000;            // 64
    float* t1   = s1 + 64;                 // 64
    float* s2   = t1 + 64;                 // 256
    float* t2   = s2 + 256;                // 256
    float* tvec = t2 + 256;                // 32*256

    int2* R     = (int2*)(tvec + 8192);    // 2*NE int2 (8B-aligned: prior total is even)
    int* cnt    = (int*)(R + 2 * NE);      // 2*NN
    int* offc   = cnt + 2 * NN;            // 2*NN+1
    int* cur    = offc + 2 * NN + 1;       // 2*NN
    int* bsum   = cur + 2 * NN;            // NB

    float* hn    = (float*)d_out;                       // 20000*256
    float* score = hn + (size_t)NN * EMBD;              // 32*20000

    hipMemsetAsync(cnt, 0, (size_t)2 * NN * 4, stream);

    k_params<<<2, 256, 0, stream>>>(b_O1, b_I1, b_S1, bn1_g, bn1_b, bn1_m, bn1_v,
                                    b_O2, b_I2, b_S2, bn2_g, bn2_b, bn2_m, bn2_v,
                                    s1, t1, s2, t2);
    k_buildBt<<<(256 * 256 + 192 * 256 + 255) / 256, 256, 0, stream>>>(
        W_O1, W_I1, W_S1, Wr1, W_O2, W_I2, W_S2, Bt1, Bt2);

    // CSR build
    k_hist<<<(NE + 255) / 256, 256, 0, stream>>>(src, dst, cnt);
    k_invdeg<<<(NN + 255) / 256, 256, 0, stream>>>(cnt, degi, dego);
    k_scanA<<<NB, 256, 0, stream>>>(cnt, bsum);
    k_scanB<<<1, 64, 0, stream>>>(bsum);
    k_scanC<<<NB, 256, 0, stream>>>(cnt, bsum, offc, cur);
    k_scatter<<<(NE + 255) / 256, 256, 0, stream>>>(src, dst, evid, cur, R);

    // C1 = node_embs @ Bt1[:,0:192]
    gemm64<<<dim3(313, 3), 256, 0, stream>>>(node_embs, NN, 256, 256, Bt1, 256,
                                             C1, 192, 0, nullptr, nullptr, nullptr, nullptr);
    // E1 = edge_embs @ Bt1[:,0:256]
    gemm64<<<dim3(8, 4), 256, 0, stream>>>(edge_embs, NR, 256, 256, Bt1, 256,
                                           E1, 256, 0, nullptr, nullptr, nullptr, nullptr);
    k_er1<<<(NR * 64 + 255) / 256, 256, 0, stream>>>(E1, br1);

    // layer-1 aggregation + combine (writes h1 into A2 cols [128,192))
    k_gather1<<<NN / 4, 256, 0, stream>>>(offc, R, C1, E1, degi, dego, s1, t1, A2);
    // layer-2 aggregation (writes A2 cols [0,128))
    k_gather2<<<NN / 4, 256, 0, stream>>>(offc, R, A2, E1, degi, dego, A2);

    // hn = tanh((A2 @ Bt2) * s2 + t2)  (or node_embs if !upd)
    gemm64<<<dim3(313, 4), 256, 0, stream>>>(A2, NN, 192, 192, Bt2, 256,
                                             hn, 256, 2, s2, t2, node_embs, upd);

    k_rels<<<BQ, 64, 0, stream>>>(edge_embs, Wr1, br1, Wr2, br2,
                                  hids, rids, tids, ihead, hn, tvec);
    k_score<<<(BQ * (NN / BQ)) / 4, 256, 0, stream>>>(hn, tvec, score);
}

// Round 5
// 203.302 us; speedup vs baseline: 2.3444x; 1.2546x over previous
//
#include <hip/hip_runtime.h>
#include <math.h>

#define NN 20000     // nodes
#define NE 320000    // edges
#define NR 500       // relations
#define EMBD 256
#define D4 64
#define BQ 32        // batch
#define TOT (2 * NN) // concatenated count length
#define NB 40        // scan blocks (40*1024 >= TOT)

typedef __attribute__((ext_vector_type(8))) short bf16x8;
typedef __attribute__((ext_vector_type(4))) float f32x4;

__device__ __forceinline__ unsigned short f2bf(float x)
{
    unsigned int u = __float_as_uint(x);
    unsigned int r = (u + 0x7fffu + ((u >> 16) & 1u)) >> 16;   // RNE
    return (unsigned short)r;
}

// ---------------- small param kernels ----------------

__global__ void k_params(const float* __restrict__ bO1, const float* __restrict__ bI1,
                         const float* __restrict__ bS1,
                         const float* __restrict__ g1, const float* __restrict__ bb1,
                         const float* __restrict__ m1, const float* __restrict__ v1,
                         const float* __restrict__ bO2, const float* __restrict__ bI2,
                         const float* __restrict__ bS2,
                         const float* __restrict__ g2, const float* __restrict__ bb2,
                         const float* __restrict__ m2, const float* __restrict__ v2,
                         float* __restrict__ s1, float* __restrict__ t1,
                         float* __restrict__ s2, float* __restrict__ t2)
{
    int i = blockIdx.x * 256 + threadIdx.x;
    if (i < 64) {
        float rsg = g1[i] / sqrtf(v1[i] + 1e-5f);
        s1[i] = rsg * (1.f / 3.f);
        t1[i] = ((bO1[i] + bI1[i] + bS1[i]) * (1.f / 3.f) - m1[i]) * rsg + bb1[i];
    } else if (i < 64 + 256) {
        int n = i - 64;
        float rsg = g2[n] / sqrtf(v2[n] + 1e-5f);
        s2[n] = rsg * (1.f / 3.f);
        t2[n] = ((bO2[n] + bI2[n] + bS2[n]) * (1.f / 3.f) - m2[n]) * rsg + bb2[n];
    }
}

// Build n-major bf16 weight blocks:
// Bn1[n][k], 256 rows x 256 k: n<64 W_O1[n][k]; <128 W_I1; <192 W_S1; <256 Wr1
// Bn2[n][k], 256 rows x 192 k: k<64 W_O2[n][k]; <128 W_I2[n][k-64]; <192 W_S2[n][k-128]
__global__ void k_buildBn(const float* __restrict__ W_O1, const float* __restrict__ W_I1,
                          const float* __restrict__ W_S1, const float* __restrict__ Wr1,
                          const float* __restrict__ W_O2, const float* __restrict__ W_I2,
                          const float* __restrict__ W_S2,
                          unsigned short* __restrict__ Bn1, unsigned short* __restrict__ Bn2)
{
    int id = blockIdx.x * 256 + threadIdx.x;
    if (id < 256 * 256) {
        int n = id >> 8, k = id & 255;
        float v;
        if (n < 64)       v = W_O1[n * 256 + k];
        else if (n < 128) v = W_I1[(n - 64) * 256 + k];
        else if (n < 192) v = W_S1[(n - 128) * 256 + k];
        else              v = Wr1[(n - 192) * 256 + k];
        Bn1[id] = f2bf(v);
    } else {
        int id2 = id - 256 * 256;
        if (id2 < 256 * 192) {
            int n = id2 / 192, k = id2 - n * 192;
            float v;
            if (k < 64)       v = W_O2[n * 64 + k];
            else if (k < 128) v = W_I2[n * 64 + (k - 64)];
            else              v = W_S2[n * 64 + (k - 128)];
            Bn2[id2] = f2bf(v);
        }
    }
}

// ---------------- CSR build ----------------

// cnt = [cnt_in | cnt_out] concatenated (length 2*NN)
__global__ void k_hist(const int* __restrict__ src, const int* __restrict__ dst,
                       int* __restrict__ cnt)
{
    int i = blockIdx.x * 256 + threadIdx.x;
    if (i < NE) {
        atomicAdd(&cnt[dst[i]], 1);
        atomicAdd(&cnt[NN + src[i]], 1);
    }
}

__global__ void k_invdeg(const int* __restrict__ cnt,
                         float* __restrict__ degi, float* __restrict__ dego)
{
    int n = blockIdx.x * 256 + threadIdx.x;
    if (n < NN) {
        degi[n] = 1.f / fmaxf((float)cnt[n], 1.f);
        dego[n] = 1.f / fmaxf((float)cnt[NN + n], 1.f);
    }
}

// phase A: per-block (1024 elems) sum -> bsum
__global__ __launch_bounds__(256) void k_scanA(const int* __restrict__ cnt,
                                               int* __restrict__ bsum)
{
    __shared__ int lds[256];
    int t = threadIdx.x;
    int base = blockIdx.x * 1024 + t * 4;
    int s = 0;
    if (base + 3 < TOT) {
        int4 v = *(const int4*)(cnt + base);
        s = v.x + v.y + v.z + v.w;
    } else {
        for (int c = 0; c < 4; ++c) { int i = base + c; if (i < TOT) s += cnt[i]; }
    }
    lds[t] = s;
    __syncthreads();
    for (int d = 128; d > 0; d >>= 1) {
        if (t < d) lds[t] += lds[t + d];
        __syncthreads();
    }
    if (t == 0) bsum[blockIdx.x] = lds[0];
}

// phase B: one wave exclusive-scans NB block sums in place
__global__ __launch_bounds__(64) void k_scanB(int* __restrict__ bsum)
{
    int t = threadIdx.x;
    int v = (t < NB) ? bsum[t] : 0;
#pragma unroll
    for (int d = 1; d < 64; d <<= 1) {
        int u = __shfl_up(v, d, 64);
        if (t >= d) v += u;
    }
    int ex = __shfl_up(v, 1, 64);
    if (t == 0) ex = 0;
    if (t < NB) bsum[t] = ex;
}

// phase C: local exclusive scan + block offset -> offc, cur
__global__ __launch_bounds__(256) void k_scanC(const int* __restrict__ cnt,
                                               const int* __restrict__ bsum,
                                               int* __restrict__ offc,
                                               int* __restrict__ cur)
{
    __shared__ int lds[256];
    int t = threadIdx.x;
    int base = blockIdx.x * 1024 + t * 4;
    int e0 = 0, e1 = 0, e2 = 0, e3 = 0;
    if (base + 3 < TOT) {
        int4 v = *(const int4*)(cnt + base);
        e0 = v.x; e1 = v.y; e2 = v.z; e3 = v.w;
    } else {
        if (base + 0 < TOT) e0 = cnt[base + 0];
        if (base + 1 < TOT) e1 = cnt[base + 1];
        if (base + 2 < TOT) e2 = cnt[base + 2];
        if (base + 3 < TOT) e3 = cnt[base + 3];
    }
    int s = e0 + e1 + e2 + e3;
    lds[t] = s;
    __syncthreads();
    for (int d = 1; d < 256; d <<= 1) {
        int u = (t >= d) ? lds[t - d] : 0;
        __syncthreads();
        lds[t] += u;
        __syncthreads();
    }
    int run = lds[t] - s + bsum[blockIdx.x];
    if (base + 3 < TOT) {
        int4 o = make_int4(run, run + e0, run + e0 + e1, run + e0 + e1 + e2);
        *(int4*)(offc + base) = o;
        *(int4*)(cur + base) = o;
    } else {
        int r = run;
        if (base + 0 < TOT) { offc[base + 0] = r; cur[base + 0] = r; r += e0; }
        if (base + 1 < TOT) { offc[base + 1] = r; cur[base + 1] = r; r += e1; }
        if (base + 2 < TOT) { offc[base + 2] = r; cur[base + 2] = r; r += e2; }
        if (base + 3 < TOT) { offc[base + 3] = r; cur[base + 3] = r; r += e3; }
    }
    if (blockIdx.x == 0 && t == 0) offc[TOT] = 2 * NE;   // grand total is fixed
}

// scatter packed edge records into combined R: in-records [0,NE), out-records [NE,2NE)
__global__ void k_scatter(const int* __restrict__ src, const int* __restrict__ dst,
                          const int* __restrict__ evid,
                          int* __restrict__ cur, int2* __restrict__ R)
{
    int e = blockIdx.x * 256 + threadIdx.x;
    if (e >= NE) return;
    int s = src[e], d = dst[e], r = evid[e];
    int p = atomicAdd(&cur[d], 1);
    R[p] = make_int2(s, r);
    int q = atomicAdd(&cur[NN + s], 1);
    R[q] = make_int2(d, r);
}

// er1 = tanh(raw + br1), in place on E1 cols [192,256)
__global__ void k_er1(float* __restrict__ E1, const float* __restrict__ br1)
{
    int id = blockIdx.x * 256 + threadIdx.x;
    if (id >= NR * 64) return;
    int r = id >> 6, j = id & 63;
    float v = E1[r * 256 + 192 + j];
    E1[r * 256 + 192 + j] = tanhf(v + br1[j]);
}

// ---------------- MFMA bf16 GEMM: C = A @ Bn^T ----------------
// A: f32 [M][lda]; Bn: bf16 n-major [>=n0+64][K] row-stride K. 64x64 tile,
// 4 waves of 32x32, BK=64, f32 accumulate. A converted f32->bf16 in staging.
// mode 0: raw f32 store (ldc). mode 2: hn epilogue tanh(acc*sv+tv) / node_embs.
__global__ __launch_bounds__(256) void gemm_mfma(
    const float* __restrict__ A, int M, int K, int lda,
    const unsigned short* __restrict__ Bn,
    float* __restrict__ C, int ldc, int mode,
    const float* __restrict__ sv, const float* __restrict__ tv,
    const float* __restrict__ node_embs, const int* __restrict__ flag)
{
    __shared__ unsigned short As[64 * 72];   // row-major [m][k], row pad to 72 (144B)
    __shared__ unsigned short Bs[64 * 72];   // row-major [n][k]
    const int t = threadIdx.x;
    const int m0 = blockIdx.x * 64, n0 = blockIdx.y * 64;
    const int lane = t & 63, wave = t >> 6;
    const int wr = wave >> 1, wc = wave & 1;          // 2x2 waves of 32x32
    const int lrow = lane & 15, lkg = lane >> 4;      // fragment row/col, k-group

    f32x4 acc[2][2] = {};                             // acc[m][n] 16x16 frags

    for (int kb = 0; kb < K; kb += 64) {
        // stage A: 64 rows x 64 k, f32 -> bf16 (4 float4 per thread)
#pragma unroll
        for (int it = 0; it < 4; ++it) {
            int idx = t + it * 256;          // [0,1024)
            int kq = idx & 15;               // k-quad
            int row = idx >> 4;              // 0..63
            int gm = m0 + row;
            float4 a = make_float4(0.f, 0.f, 0.f, 0.f);
            if (gm < M) a = *(const float4*)(A + (size_t)gm * lda + kb + 4 * kq);
            unsigned int p0 = (unsigned int)f2bf(a.x) | ((unsigned int)f2bf(a.y) << 16);
            unsigned int p1 = (unsigned int)f2bf(a.z) | ((unsigned int)f2bf(a.w) << 16);
            *(uint2*)&As[row * 72 + 4 * kq] = make_uint2(p0, p1);
        }
        // stage B: 64 n-rows x 64 k bf16 (uint4 = 8 bf16; 2 iters per thread)
#pragma unroll
        for (int it = 0; it < 2; ++it) {
            int idx = t + it * 256;          // [0,512)
            int ko = idx & 7;                // k-oct
            int row = idx >> 3;              // 0..63
            uint4 b = *(const uint4*)(Bn + (size_t)(n0 + row) * K + kb + 8 * ko);
            *(uint4*)&Bs[row * 72 + 8 * ko] = b;
        }
        __syncthreads();
#pragma unroll
        for (int ks = 0; ks < 2; ++ks) {
            int k0 = ks * 32 + lkg * 8;
            bf16x8 af0 = *(const bf16x8*)&As[(wr * 32 + lrow) * 72 + k0];
            bf16x8 af1 = *(const bf16x8*)&As[(wr * 32 + 16 + lrow) * 72 + k0];
            bf16x8 bf0 = *(const bf16x8*)&Bs[(wc * 32 + lrow) * 72 + k0];
            bf16x8 bf1 = *(const bf16x8*)&Bs[(wc * 32 + 16 + lrow) * 72 + k0];
            acc[0][0] = __builtin_amdgcn_mfma_f32_16x16x32_bf16(af0, bf0, acc[0][0], 0, 0, 0);
            acc[0][1] = __builtin_amdgcn_mfma_f32_16x16x32_bf16(af0, bf1, acc[0][1], 0, 0, 0);
            acc[1][0] = __builtin_amdgcn_mfma_f32_16x16x32_bf16(af1, bf0, acc[1][0], 0, 0, 0);
            acc[1][1] = __builtin_amdgcn_mfma_f32_16x16x32_bf16(af1, bf1, acc[1][1], 0, 0, 0);
        }
        __syncthreads();
    }

    // epilogue: C/D frag layout col = lane&15, row = (lane>>4)*4 + r  [m89]
#pragma unroll
    for (int m = 0; m < 2; ++m) {
#pragma unroll
        for (int r = 0; r < 4; ++r) {
            int gm = m0 + wr * 32 + m * 16 + lkg * 4 + r;
            if (gm >= M) continue;
#pragma unroll
            for (int n = 0; n < 2; ++n) {
                int gn = n0 + wc * 32 + n * 16 + lrow;
                float v = acc[m][n][r];
                if (mode == 0) {
                    C[(size_t)gm * ldc + gn] = v;
                } else {
                    float val = tanhf(v * sv[gn] + tv[gn]);
                    if (flag[0] == 0) val = node_embs[(size_t)gm * EMBD + gn];
                    C[(size_t)gm * EMBD + gn] = val;
                }
            }
        }
    }
}

// ---------------- CSR gather aggregation, MLP-unrolled ----------------
// Each wave owns one node; lane = dim. Records are staged per-lane (one
// coalesced load per 64 records) and broadcast via shfl; row gathers are
// 4x unrolled so 8 independent 256B loads are in flight per wave.

__device__ __forceinline__ float gather_range(
    const int2* __restrict__ R, int r0, int r1, int j,
    const float* __restrict__ TAB, int ldt, int toff,
    const float* __restrict__ ETAB, int eoff)
{
    float acc = 0.f;
    int cnt = r1 - r0;
    for (int base = 0; base < cnt; base += 64) {
        int rem = cnt - base; if (rem > 64) rem = 64;
        int2 myrec = make_int2(0, 0);
        if (j < rem) myrec = R[r0 + base + j];
        int i = 0;
        for (; i + 4 <= rem; i += 4) {
            int x0 = __shfl(myrec.x, i, 64),     y0 = __shfl(myrec.y, i, 64);
            int x1 = __shfl(myrec.x, i + 1, 64), y1 = __shfl(myrec.y, i + 1, 64);
            int x2 = __shfl(myrec.x, i + 2, 64), y2 = __shfl(myrec.y, i + 2, 64);
            int x3 = __shfl(myrec.x, i + 3, 64), y3 = __shfl(myrec.y, i + 3, 64);
            float a0 = TAB[(size_t)x0 * ldt + toff + j];
            float a1 = TAB[(size_t)x1 * ldt + toff + j];
            float a2 = TAB[(size_t)x2 * ldt + toff + j];
            float a3 = TAB[(size_t)x3 * ldt + toff + j];
            float e0 = ETAB[(size_t)y0 * 256 + eoff + j];
            float e1 = ETAB[(size_t)y1 * 256 + eoff + j];
            float e2 = ETAB[(size_t)y2 * 256 + eoff + j];
            float e3 = ETAB[(size_t)y3 * 256 + eoff + j];
            acc += (a0 - e0) + (a1 - e1) + (a2 - e2) + (a3 - e3);
        }
        for (; i < rem; ++i) {
            int x = __shfl(myrec.x, i, 64), y = __shfl(myrec.y, i, 64);
            acc += TAB[(size_t)x * ldt + toff + j] - ETAB[(size_t)y * 256 + eoff + j];
        }
    }
    return acc;
}

// layer 1 fused with combine: h1 = tanh((accO/degi + accI/dego + hS1raw)*s1 + t1)
__global__ __launch_bounds__(256) void k_gather1(
    const int* __restrict__ offc, const int2* __restrict__ R,
    const float* __restrict__ C1, const float* __restrict__ E1,
    const float* __restrict__ invdegi, const float* __restrict__ invdego,
    const float* __restrict__ s1, const float* __restrict__ t1,
    float* __restrict__ A2)
{
    int n = blockIdx.x * 4 + (threadIdx.x >> 6);
    if (n >= NN) return;
    int j = threadIdx.x & 63;
    float accO = gather_range(R, offc[n], offc[n + 1], j, C1, 192, 0, E1, 0);
    float accI = gather_range(R, offc[NN + n], offc[NN + n + 1], j, C1, 192, 64, E1, 64);
    float x = accO * invdegi[n] + accI * invdego[n] + C1[(size_t)n * 192 + 128 + j];
    A2[(size_t)n * 192 + 128 + j] = tanhf(x * s1[j] + t1[j]);
}

// layer 2: aggregate h1 (A2 cols[128,192)) minus er1 (E1 cols[192,256)); write A2 cols [0,128)
__global__ __launch_bounds__(256) void k_gather2(
    const int* __restrict__ offc, const int2* __restrict__ R,
    const float* __restrict__ A2r, const float* __restrict__ E1,
    const float* __restrict__ invdegi, const float* __restrict__ invdego,
    float* __restrict__ A2w)
{
    int n = blockIdx.x * 4 + (threadIdx.x >> 6);
    if (n >= NN) return;
    int j = threadIdx.x & 63;
    float accO = gather_range(R, offc[n], offc[n + 1], j, A2r, 192, 128, E1, 192);
    float accI = gather_range(R, offc[NN + n], offc[NN + n + 1], j, A2r, 192, 128, E1, 192);
    A2w[(size_t)n * 192 + j]      = accO * invdegi[n];
    A2w[(size_t)n * 192 + 64 + j] = accI * invdego[n];
}

// ---------------- scoring ----------------
__global__ __launch_bounds__(64) void k_rels(
    const float* __restrict__ edge_embs,
    const float* __restrict__ Wr1, const float* __restrict__ br1,
    const float* __restrict__ Wr2, const float* __restrict__ br2,
    const int* __restrict__ hids, const int* __restrict__ rids, const int* __restrict__ tids,
    const int* __restrict__ is_head, const float* __restrict__ hn,
    float* __restrict__ tvec)
{
    __shared__ float e_s[256];
    __shared__ float m_s[64];
    int b = blockIdx.x, o = threadIdx.x;
    int rid = rids[b];
#pragma unroll
    for (int q = 0; q < 4; ++q) e_s[o + 64 * q] = edge_embs[(size_t)rid * 256 + o + 64 * q];
    __syncthreads();
    float acc = br1[o];
    for (int k = 0; k < 256; ++k) acc = fmaf(e_s[k], Wr1[o * 256 + k], acc);
    m_s[o] = fmaxf(acc, 0.f);
    __syncthreads();
    int ih = is_head[0];
    int nid = ih ? tids[b] : hids[b];
#pragma unroll
    for (int q = 0; q < 4; ++q) {
        int n = o + 64 * q;
        float r = br2[n];
        for (int jj = 0; jj < 64; ++jj) r = fmaf(m_s[jj], Wr2[n * 64 + jj], r);
        float hv = hn[(size_t)nid * 256 + n];
        tvec[b * 256 + n] = ih ? (hv - r) : (hv + r);
    }
}

__global__ __launch_bounds__(256) void k_score(
    const float* __restrict__ hn, const float* __restrict__ tvec,
    float* __restrict__ score)
{
    int p = blockIdx.x * 4 + (threadIdx.x >> 6);
    if (p >= BQ * (NN / BQ)) return;
    int l = threadIdx.x & 63;
    int b = p / (NN / BQ);
    int j = p - b * (NN / BQ);
    int idx = (b * NN + 32 * j) / BQ;   // faithful repeat_interleave indexing
    float ssum = 0.f;
#pragma unroll
    for (int q = 0; q < 4; ++q) {
        float df = hn[(size_t)idx * 256 + l + 64 * q] - tvec[b * 256 + l + 64 * q];
        ssum = fmaf(df, df, ssum);
    }
#pragma unroll
    for (int off = 32; off >= 1; off >>= 1) ssum += __shfl_xor(ssum, off, 64);
    float dist = sqrtf(ssum);
    float sc = 1.f / (1.f + expf(dist - 12.f));
    if (l < 32) score[(size_t)b * NN + 32 * j + l] = sc;
}

// ---------------- launch ----------------
extern "C" void kernel_launch(void* const* d_in, const int* in_sizes, int n_in,
                              void* d_out, int out_size, void* d_ws, size_t ws_size,
                              hipStream_t stream)
{
    const float* node_embs = (const float*)d_in[0];
    const float* edge_embs = (const float*)d_in[1];
    const float* W_O1 = (const float*)d_in[2];  const float* b_O1 = (const float*)d_in[3];
    const float* W_I1 = (const float*)d_in[4];  const float* b_I1 = (const float*)d_in[5];
    const float* W_S1 = (const float*)d_in[6];  const float* b_S1 = (const float*)d_in[7];
    const float* bn1_g = (const float*)d_in[8]; const float* bn1_b = (const float*)d_in[9];
    const float* bn1_m = (const float*)d_in[10];const float* bn1_v = (const float*)d_in[11];
    const float* Wr1 = (const float*)d_in[12];  const float* br1 = (const float*)d_in[13];
    const float* W_O2 = (const float*)d_in[14]; const float* b_O2 = (const float*)d_in[15];
    const float* W_I2 = (const float*)d_in[16]; const float* b_I2 = (const float*)d_in[17];
    const float* W_S2 = (const float*)d_in[18]; const float* b_S2 = (const float*)d_in[19];
    const float* bn2_g = (const float*)d_in[20];const float* bn2_b = (const float*)d_in[21];
    const float* bn2_m = (const float*)d_in[22];const float* bn2_v = (const float*)d_in[23];
    const float* Wr2 = (const float*)d_in[24];  const float* br2 = (const float*)d_in[25];
    const int* src = (const int*)d_in[26];
    const int* dst = (const int*)d_in[27];
    const int* evid = (const int*)d_in[28];
    const int* hids = (const int*)d_in[29];
    const int* rids = (const int*)d_in[30];
    const int* tids = (const int*)d_in[31];
    const int* upd = (const int*)d_in[32];
    const int* ihead = (const int*)d_in[33];

    float* ws = (float*)d_ws;
    float* C1   = ws;                      // 20000*192  : [hO1 | hI1 | hS1raw]
    float* A2   = C1 + 3840000;            // 20000*192  : [agg2O' | agg2I' | h1]
    float* E1   = A2 + 3840000;            // 500*256    : [eO1 | eI1 | (unused) | er1]
    unsigned short* Bn1 = (unsigned short*)(E1 + 128000);  // 256*256 bf16 (32768 floats)
    unsigned short* Bn2 = Bn1 + 65536;                     // 256*192 bf16 (24576 floats)
    float* degi = (float*)(Bn2 + 49152);   // 20000 (invdeg_in)
    float* dego = degi + 20000;            // 20000 (invdeg_out)
    float* s1   = dego + 20000;            // 64
    float* t1   = s1 + 64;                 // 64
    float* s2   = t1 + 64;                 // 256
    float* t2   = s2 + 256;                // 256
    float* tvec = t2 + 256;                // 32*256

    int2* R     = (int2*)(tvec + 8192);    // 2*NE int2
    int* cnt    = (int*)(R + 2 * NE);      // 2*NN
    int* offc   = cnt + 2 * NN;            // 2*NN+1
    int* cur    = offc + 2 * NN + 1;       // 2*NN
    int* bsum   = cur + 2 * NN;            // NB

    float* hn    = (float*)d_out;                       // 20000*256
    float* score = hn + (size_t)NN * EMBD;              // 32*20000

    hipMemsetAsync(cnt, 0, (size_t)2 * NN * 4, stream);

    k_params<<<2, 256, 0, stream>>>(b_O1, b_I1, b_S1, bn1_g, bn1_b, bn1_m, bn1_v,
                                    b_O2, b_I2, b_S2, bn2_g, bn2_b, bn2_m, bn2_v,
                                    s1, t1, s2, t2);
    k_buildBn<<<(256 * 256 + 256 * 192 + 255) / 256, 256, 0, stream>>>(
        W_O1, W_I1, W_S1, Wr1, W_O2, W_I2, W_S2, Bn1, Bn2);

    // CSR build
    k_hist<<<(NE + 255) / 256, 256, 0, stream>>>(src, dst, cnt);
    k_invdeg<<<(NN + 255) / 256, 256, 0, stream>>>(cnt, degi, dego);
    k_scanA<<<NB, 256, 0, stream>>>(cnt, bsum);
    k_scanB<<<1, 64, 0, stream>>>(bsum);
    k_scanC<<<NB, 256, 0, stream>>>(cnt, bsum, offc, cur);
    k_scatter<<<(NE + 255) / 256, 256, 0, stream>>>(src, dst, evid, cur, R);

    // C1 = node_embs @ Bn1[0:192]^T   (M=20000, K=256)
    gemm_mfma<<<dim3(313, 3), 256, 0, stream>>>(node_embs, NN, 256, 256, Bn1,
                                                C1, 192, 0, nullptr, nullptr, nullptr, nullptr);
    // E1 = edge_embs @ Bn1^T          (M=500, K=256)
    gemm_mfma<<<dim3(8, 4), 256, 0, stream>>>(edge_embs, NR, 256, 256, Bn1,
                                              E1, 256, 0, nullptr, nullptr, nullptr, nullptr);
    k_er1<<<(NR * 64 + 255) / 256, 256, 0, stream>>>(E1, br1);

    // layer-1 aggregation + combine (writes h1 into A2 cols [128,192))
    k_gather1<<<NN / 4, 256, 0, stream>>>(offc, R, C1, E1, degi, dego, s1, t1, A2);
    // layer-2 aggregation (writes A2 cols [0,128))
    k_gather2<<<NN / 4, 256, 0, stream>>>(offc, R, A2, E1, degi, dego, A2);

    // hn = tanh((A2 @ Bn2^T) * s2 + t2)  (or node_embs if !upd)  (M=20000, K=192)
    gemm_mfma<<<dim3(313, 4), 256, 0, stream>>>(A2, NN, 192, 192, Bn2,
                                                hn, 256, 2, s2, t2, node_embs, upd);

    k_rels<<<BQ, 64, 0, stream>>>(edge_embs, Wr1, br1, Wr2, br2,
                                  hids, rids, tids, ihead, hn, tvec);
    k_score<<<(BQ * (NN / BQ)) / 4, 256, 0, stream>>>(hn, tvec, score);
}

// Round 6
// 198.454 us; speedup vs baseline: 2.4017x; 1.0244x over previous
//
#include <hip/hip_runtime.h>
#include <math.h>

#define NN 20000     // nodes
#define NE 320000    // edges
#define NR 500       // relations
#define EMBD 256
#define D4 64
#define BQ 32        // batch
#define TOT (2 * NN) // concatenated count length
#define NB 40        // scan blocks (40*1024 >= TOT)
#define NBLK_BN 448  // buildBn data blocks

typedef __attribute__((ext_vector_type(8))) short bf16x8;
typedef __attribute__((ext_vector_type(4))) float f32x4;

__device__ __forceinline__ unsigned short f2bf(float x)
{
    unsigned int u = __float_as_uint(x);
    unsigned int r = (u + 0x7fffu + ((u >> 16) & 1u)) >> 16;   // RNE
    return (unsigned short)r;
}

// ---------------- weight pack + folded param kernel ----------------
// blocks [0,448): build bf16 n-major weight blocks.
// blocks 448,449: fused BN/bias scale-offset precompute.
__global__ void k_buildBn(const float* __restrict__ W_O1, const float* __restrict__ W_I1,
                          const float* __restrict__ W_S1, const float* __restrict__ Wr1,
                          const float* __restrict__ W_O2, const float* __restrict__ W_I2,
                          const float* __restrict__ W_S2,
                          unsigned short* __restrict__ Bn1, unsigned short* __restrict__ Bn2,
                          const float* __restrict__ bO1, const float* __restrict__ bI1,
                          const float* __restrict__ bS1,
                          const float* __restrict__ g1, const float* __restrict__ bb1,
                          const float* __restrict__ m1, const float* __restrict__ v1,
                          const float* __restrict__ bO2, const float* __restrict__ bI2,
                          const float* __restrict__ bS2,
                          const float* __restrict__ g2, const float* __restrict__ bb2,
                          const float* __restrict__ m2, const float* __restrict__ v2,
                          float* __restrict__ s1, float* __restrict__ t1,
                          float* __restrict__ s2, float* __restrict__ t2)
{
    int b = blockIdx.x;
    if (b >= NBLK_BN) {
        int i = (b - NBLK_BN) * 256 + threadIdx.x;   // [0,512)
        if (i < 64) {
            float rsg = g1[i] / sqrtf(v1[i] + 1e-5f);
            s1[i] = rsg * (1.f / 3.f);
            t1[i] = ((bO1[i] + bI1[i] + bS1[i]) * (1.f / 3.f) - m1[i]) * rsg + bb1[i];
        } else if (i < 320) {
            int n = i - 64;
            float rsg = g2[n] / sqrtf(v2[n] + 1e-5f);
            s2[n] = rsg * (1.f / 3.f);
            t2[n] = ((bO2[n] + bI2[n] + bS2[n]) * (1.f / 3.f) - m2[n]) * rsg + bb2[n];
        }
        return;
    }
    int id = b * 256 + threadIdx.x;
    if (id < 256 * 256) {
        int n = id >> 8, k = id & 255;
        float v;
        if (n < 64)       v = W_O1[n * 256 + k];
        else if (n < 128) v = W_I1[(n - 64) * 256 + k];
        else if (n < 192) v = W_S1[(n - 128) * 256 + k];
        else              v = Wr1[(n - 192) * 256 + k];
        Bn1[id] = f2bf(v);
    } else {
        int id2 = id - 256 * 256;
        if (id2 < 256 * 192) {
            int n = id2 / 192, k = id2 - n * 192;
            float v;
            if (k < 64)       v = W_O2[n * 64 + k];
            else if (k < 128) v = W_I2[n * 64 + (k - 64)];
            else              v = W_S2[n * 64 + (k - 128)];
            Bn2[id2] = f2bf(v);
        }
    }
}

// ---------------- CSR build ----------------

// cnt = [cnt_in | cnt_out] concatenated (length 2*NN)
__global__ void k_hist(const int* __restrict__ src, const int* __restrict__ dst,
                       int* __restrict__ cnt)
{
    int i = blockIdx.x * 256 + threadIdx.x;
    if (i < NE) {
        atomicAdd(&cnt[dst[i]], 1);
        atomicAdd(&cnt[NN + src[i]], 1);
    }
}

// phase A: per-block (1024 elems) sum -> bsum
__global__ __launch_bounds__(256) void k_scanA(const int* __restrict__ cnt,
                                               int* __restrict__ bsum)
{
    __shared__ int lds[256];
    int t = threadIdx.x;
    int base = blockIdx.x * 1024 + t * 4;
    int s = 0;
    if (base + 3 < TOT) {
        int4 v = *(const int4*)(cnt + base);
        s = v.x + v.y + v.z + v.w;
    } else {
        for (int c = 0; c < 4; ++c) { int i = base + c; if (i < TOT) s += cnt[i]; }
    }
    lds[t] = s;
    __syncthreads();
    for (int d = 128; d > 0; d >>= 1) {
        if (t < d) lds[t] += lds[t + d];
        __syncthreads();
    }
    if (t == 0) bsum[blockIdx.x] = lds[0];
}

// phase B: one wave exclusive-scans NB block sums in place
__global__ __launch_bounds__(64) void k_scanB(int* __restrict__ bsum)
{
    int t = threadIdx.x;
    int v = (t < NB) ? bsum[t] : 0;
#pragma unroll
    for (int d = 1; d < 64; d <<= 1) {
        int u = __shfl_up(v, d, 64);
        if (t >= d) v += u;
    }
    int ex = __shfl_up(v, 1, 64);
    if (t == 0) ex = 0;
    if (t < NB) bsum[t] = ex;
}

// phase C: local exclusive scan + block offset -> offc, cur; fused invdeg
__global__ __launch_bounds__(256) void k_scanC(const int* __restrict__ cnt,
                                               const int* __restrict__ bsum,
                                               int* __restrict__ offc,
                                               int* __restrict__ cur,
                                               float* __restrict__ degi,
                                               float* __restrict__ dego)
{
    __shared__ int lds[256];
    int t = threadIdx.x;
    int base = blockIdx.x * 1024 + t * 4;
    int e0 = 0, e1 = 0, e2 = 0, e3 = 0;
    if (base + 3 < TOT) {
        int4 v = *(const int4*)(cnt + base);
        e0 = v.x; e1 = v.y; e2 = v.z; e3 = v.w;
    } else {
        if (base + 0 < TOT) e0 = cnt[base + 0];
        if (base + 1 < TOT) e1 = cnt[base + 1];
        if (base + 2 < TOT) e2 = cnt[base + 2];
        if (base + 3 < TOT) e3 = cnt[base + 3];
    }
    // fused invdeg
    {
        int ids[4] = {base, base + 1, base + 2, base + 3};
        int es[4] = {e0, e1, e2, e3};
#pragma unroll
        for (int c = 0; c < 4; ++c) {
            int idx = ids[c];
            if (idx < NN) degi[idx] = 1.f / fmaxf((float)es[c], 1.f);
            else if (idx < TOT) dego[idx - NN] = 1.f / fmaxf((float)es[c], 1.f);
        }
    }
    int s = e0 + e1 + e2 + e3;
    lds[t] = s;
    __syncthreads();
    for (int d = 1; d < 256; d <<= 1) {
        int u = (t >= d) ? lds[t - d] : 0;
        __syncthreads();
        lds[t] += u;
        __syncthreads();
    }
    int run = lds[t] - s + bsum[blockIdx.x];
    if (base + 3 < TOT) {
        int4 o = make_int4(run, run + e0, run + e0 + e1, run + e0 + e1 + e2);
        *(int4*)(offc + base) = o;
        *(int4*)(cur + base) = o;
    } else {
        int r = run;
        if (base + 0 < TOT) { offc[base + 0] = r; cur[base + 0] = r; r += e0; }
        if (base + 1 < TOT) { offc[base + 1] = r; cur[base + 1] = r; r += e1; }
        if (base + 2 < TOT) { offc[base + 2] = r; cur[base + 2] = r; r += e2; }
        if (base + 3 < TOT) { offc[base + 3] = r; cur[base + 3] = r; r += e3; }
    }
    if (blockIdx.x == 0 && t == 0) offc[TOT] = 2 * NE;   // grand total is fixed
}

// scatter PACKED records (other | evid<<15) into combined R
__global__ void k_scatter(const int* __restrict__ src, const int* __restrict__ dst,
                          const int* __restrict__ evid,
                          int* __restrict__ cur, unsigned* __restrict__ R)
{
    int e = blockIdx.x * 256 + threadIdx.x;
    if (e >= NE) return;
    int s = src[e], d = dst[e];
    unsigned rv = (unsigned)evid[e] << 15;
    int p = atomicAdd(&cur[d], 1);
    R[p] = (unsigned)s | rv;
    int q = atomicAdd(&cur[NN + s], 1);
    R[q] = (unsigned)d | rv;
}

// ---------------- MFMA bf16 GEMM: C = A @ Bn^T ----------------
// mode 0: raw f32 store (ldc).
// mode 1: E1 epilogue — raw for gn<192, tanh(v + sv[gn-192]) for gn>=192 (fused er1).
// mode 2: hn epilogue tanh(acc*sv+tv) / node_embs passthrough.
__global__ __launch_bounds__(256) void gemm_mfma(
    const float* __restrict__ A, int M, int K, int lda,
    const unsigned short* __restrict__ Bn,
    float* __restrict__ C, int ldc, int mode,
    const float* __restrict__ sv, const float* __restrict__ tv,
    const float* __restrict__ node_embs, const int* __restrict__ flag)
{
    __shared__ unsigned short As[64 * 72];   // row-major [m][k], row pad to 72 (144B)
    __shared__ unsigned short Bs[64 * 72];   // row-major [n][k]
    const int t = threadIdx.x;
    const int m0 = blockIdx.x * 64, n0 = blockIdx.y * 64;
    const int lane = t & 63, wave = t >> 6;
    const int wr = wave >> 1, wc = wave & 1;          // 2x2 waves of 32x32
    const int lrow = lane & 15, lkg = lane >> 4;      // fragment row/col, k-group

    f32x4 acc[2][2] = {};                             // acc[m][n] 16x16 frags

    for (int kb = 0; kb < K; kb += 64) {
#pragma unroll
        for (int it = 0; it < 4; ++it) {
            int idx = t + it * 256;          // [0,1024)
            int kq = idx & 15;               // k-quad
            int row = idx >> 4;              // 0..63
            int gm = m0 + row;
            float4 a = make_float4(0.f, 0.f, 0.f, 0.f);
            if (gm < M) a = *(const float4*)(A + (size_t)gm * lda + kb + 4 * kq);
            unsigned int p0 = (unsigned int)f2bf(a.x) | ((unsigned int)f2bf(a.y) << 16);
            unsigned int p1 = (unsigned int)f2bf(a.z) | ((unsigned int)f2bf(a.w) << 16);
            *(uint2*)&As[row * 72 + 4 * kq] = make_uint2(p0, p1);
        }
#pragma unroll
        for (int it = 0; it < 2; ++it) {
            int idx = t + it * 256;          // [0,512)
            int ko = idx & 7;                // k-oct
            int row = idx >> 3;              // 0..63
            uint4 b = *(const uint4*)(Bn + (size_t)(n0 + row) * K + kb + 8 * ko);
            *(uint4*)&Bs[row * 72 + 8 * ko] = b;
        }
        __syncthreads();
#pragma unroll
        for (int ks = 0; ks < 2; ++ks) {
            int k0 = ks * 32 + lkg * 8;
            bf16x8 af0 = *(const bf16x8*)&As[(wr * 32 + lrow) * 72 + k0];
            bf16x8 af1 = *(const bf16x8*)&As[(wr * 32 + 16 + lrow) * 72 + k0];
            bf16x8 bf0 = *(const bf16x8*)&Bs[(wc * 32 + lrow) * 72 + k0];
            bf16x8 bf1 = *(const bf16x8*)&Bs[(wc * 32 + 16 + lrow) * 72 + k0];
            acc[0][0] = __builtin_amdgcn_mfma_f32_16x16x32_bf16(af0, bf0, acc[0][0], 0, 0, 0);
            acc[0][1] = __builtin_amdgcn_mfma_f32_16x16x32_bf16(af0, bf1, acc[0][1], 0, 0, 0);
            acc[1][0] = __builtin_amdgcn_mfma_f32_16x16x32_bf16(af1, bf0, acc[1][0], 0, 0, 0);
            acc[1][1] = __builtin_amdgcn_mfma_f32_16x16x32_bf16(af1, bf1, acc[1][1], 0, 0, 0);
        }
        __syncthreads();
    }

    // epilogue: C/D frag layout col = lane&15, row = (lane>>4)*4 + r  [m89]
#pragma unroll
    for (int m = 0; m < 2; ++m) {
#pragma unroll
        for (int r = 0; r < 4; ++r) {
            int gm = m0 + wr * 32 + m * 16 + lkg * 4 + r;
            if (gm >= M) continue;
#pragma unroll
            for (int n = 0; n < 2; ++n) {
                int gn = n0 + wc * 32 + n * 16 + lrow;
                float v = acc[m][n][r];
                if (mode == 0) {
                    C[(size_t)gm * ldc + gn] = v;
                } else if (mode == 1) {
                    float val = (gn >= 192) ? tanhf(v + sv[gn - 192]) : v;
                    C[(size_t)gm * ldc + gn] = val;
                } else {
                    float val = tanhf(v * sv[gn] + tv[gn]);
                    if (flag[0] == 0) val = node_embs[(size_t)gm * EMBD + gn];
                    C[(size_t)gm * EMBD + gn] = val;
                }
            }
        }
    }
}

// ---------------- CSR gather, quad-group float4 rows ----------------
// Wave = 1 node. 4 groups of 16 lanes; group g handles records 4i+g and loads
// whole 64-dim rows as float4 (lane q -> dims 4q..4q+3). 4x unrolled => up to
// 8 KB outstanding per wave. Cross-group shfl_xor reduce at the end.

__device__ __forceinline__ void gather_quad(
    const unsigned* __restrict__ R, int r0, int r1, int g, int q,
    const float* __restrict__ TAB, int ldt, int toff,
    const float* __restrict__ ETAB, int eoff,
    float4& acc)
{
    int lane = g * 16 + q;
    int cnt = r1 - r0;
    for (int base = 0; base < cnt; base += 64) {
        int rem = cnt - base; if (rem > 64) rem = 64;
        unsigned rec = 0u;
        if (lane < rem) rec = R[r0 + base + lane];
        int i = 0;
        for (; 4 * i + 15 < rem; i += 4) {                    // wave-uniform
            unsigned ra = __shfl(rec, 4 * i + g, 64);
            unsigned rb = __shfl(rec, 4 * i + 4 + g, 64);
            unsigned rc = __shfl(rec, 4 * i + 8 + g, 64);
            unsigned rd = __shfl(rec, 4 * i + 12 + g, 64);
            float4 a0 = *(const float4*)(TAB + (size_t)(ra & 0x7FFFu) * ldt + toff + 4 * q);
            float4 e0 = *(const float4*)(ETAB + (size_t)(ra >> 15) * 256 + eoff + 4 * q);
            float4 a1 = *(const float4*)(TAB + (size_t)(rb & 0x7FFFu) * ldt + toff + 4 * q);
            float4 e1 = *(const float4*)(ETAB + (size_t)(rb >> 15) * 256 + eoff + 4 * q);
            float4 a2 = *(const float4*)(TAB + (size_t)(rc & 0x7FFFu) * ldt + toff + 4 * q);
            float4 e2 = *(const float4*)(ETAB + (size_t)(rc >> 15) * 256 + eoff + 4 * q);
            float4 a3 = *(const float4*)(TAB + (size_t)(rd & 0x7FFFu) * ldt + toff + 4 * q);
            float4 e3 = *(const float4*)(ETAB + (size_t)(rd >> 15) * 256 + eoff + 4 * q);
            acc.x += (a0.x - e0.x) + (a1.x - e1.x) + (a2.x - e2.x) + (a3.x - e3.x);
            acc.y += (a0.y - e0.y) + (a1.y - e1.y) + (a2.y - e2.y) + (a3.y - e3.y);
            acc.z += (a0.z - e0.z) + (a1.z - e1.z) + (a2.z - e2.z) + (a3.z - e3.z);
            acc.w += (a0.w - e0.w) + (a1.w - e1.w) + (a2.w - e2.w) + (a3.w - e3.w);
        }
        for (; 4 * i < rem; ++i) {                            // wave-uniform bound
            int idx = 4 * i + g;
            unsigned rr = __shfl(rec, idx < rem ? idx : 0, 64);
            if (idx < rem) {
                float4 a = *(const float4*)(TAB + (size_t)(rr & 0x7FFFu) * ldt + toff + 4 * q);
                float4 e = *(const float4*)(ETAB + (size_t)(rr >> 15) * 256 + eoff + 4 * q);
                acc.x += a.x - e.x; acc.y += a.y - e.y;
                acc.z += a.z - e.z; acc.w += a.w - e.w;
            }
        }
    }
}

__device__ __forceinline__ void xreduce(float4& v)
{
    v.x += __shfl_xor(v.x, 16, 64); v.y += __shfl_xor(v.y, 16, 64);
    v.z += __shfl_xor(v.z, 16, 64); v.w += __shfl_xor(v.w, 16, 64);
    v.x += __shfl_xor(v.x, 32, 64); v.y += __shfl_xor(v.y, 32, 64);
    v.z += __shfl_xor(v.z, 32, 64); v.w += __shfl_xor(v.w, 32, 64);
}

// layer 1 fused with combine: h1 = tanh((accO/degi + accI/dego + hS1raw)*s1 + t1)
__global__ __launch_bounds__(256) void k_gather1(
    const int* __restrict__ offc, const unsigned* __restrict__ R,
    const float* __restrict__ C1, const float* __restrict__ E1,
    const float* __restrict__ invdegi, const float* __restrict__ invdego,
    const float* __restrict__ s1, const float* __restrict__ t1,
    float* __restrict__ A2)
{
    int n = blockIdx.x * 4 + (threadIdx.x >> 6);
    if (n >= NN) return;
    int lane = threadIdx.x & 63, g = lane >> 4, q = lane & 15;
    float4 accO = make_float4(0.f, 0.f, 0.f, 0.f);
    float4 accI = make_float4(0.f, 0.f, 0.f, 0.f);
    gather_quad(R, offc[n], offc[n + 1], g, q, C1, 192, 0, E1, 0, accO);
    gather_quad(R, offc[NN + n], offc[NN + n + 1], g, q, C1, 192, 64, E1, 64, accI);
    xreduce(accO);
    xreduce(accI);
    if (g == 0) {
        float di = invdegi[n], dh = invdego[n];
        float4 hs = *(const float4*)(C1 + (size_t)n * 192 + 128 + 4 * q);
        float4 sv = *(const float4*)(s1 + 4 * q);
        float4 tv = *(const float4*)(t1 + 4 * q);
        float4 o;
        o.x = tanhf((accO.x * di + accI.x * dh + hs.x) * sv.x + tv.x);
        o.y = tanhf((accO.y * di + accI.y * dh + hs.y) * sv.y + tv.y);
        o.z = tanhf((accO.z * di + accI.z * dh + hs.z) * sv.z + tv.z);
        o.w = tanhf((accO.w * di + accI.w * dh + hs.w) * sv.w + tv.w);
        *(float4*)(A2 + (size_t)n * 192 + 128 + 4 * q) = o;
    }
}

// layer 2: aggregate h1 (A2 cols[128,192)) minus er1 (E1 cols[192,256)); write A2 cols [0,128)
__global__ __launch_bounds__(256) void k_gather2(
    const int* __restrict__ offc, const unsigned* __restrict__ R,
    const float* __restrict__ A2r, const float* __restrict__ E1,
    const float* __restrict__ invdegi, const float* __restrict__ invdego,
    float* __restrict__ A2w)
{
    int n = blockIdx.x * 4 + (threadIdx.x >> 6);
    if (n >= NN) return;
    int lane = threadIdx.x & 63, g = lane >> 4, q = lane & 15;
    float4 accO = make_float4(0.f, 0.f, 0.f, 0.f);
    float4 accI = make_float4(0.f, 0.f, 0.f, 0.f);
    gather_quad(R, offc[n], offc[n + 1], g, q, A2r, 192, 128, E1, 192, accO);
    gather_quad(R, offc[NN + n], offc[NN + n + 1], g, q, A2r, 192, 128, E1, 192, accI);
    xreduce(accO);
    xreduce(accI);
    if (g == 0) {
        float di = invdegi[n], dh = invdego[n];
        float4 o0, o1;
        o0.x = accO.x * di; o0.y = accO.y * di; o0.z = accO.z * di; o0.w = accO.w * di;
        o1.x = accI.x * dh; o1.y = accI.y * dh; o1.z = accI.z * dh; o1.w = accI.w * dh;
        *(float4*)(A2w + (size_t)n * 192 + 4 * q) = o0;
        *(float4*)(A2w + (size_t)n * 192 + 64 + 4 * q) = o1;
    }
}

// ---------------- scoring ----------------
__global__ __launch_bounds__(64) void k_rels(
    const float* __restrict__ edge_embs,
    const float* __restrict__ Wr1, const float* __restrict__ br1,
    const float* __restrict__ Wr2, const float* __restrict__ br2,
    const int* __restrict__ hids, const int* __restrict__ rids, const int* __restrict__ tids,
    const int* __restrict__ is_head, const float* __restrict__ hn,
    float* __restrict__ tvec)
{
    __shared__ float e_s[256];
    __shared__ float m_s[64];
    int b = blockIdx.x, o = threadIdx.x;
    int rid = rids[b];
#pragma unroll
    for (int q = 0; q < 4; ++q) e_s[o + 64 * q] = edge_embs[(size_t)rid * 256 + o + 64 * q];
    __syncthreads();
    float acc = br1[o];
    for (int k = 0; k < 256; ++k) acc = fmaf(e_s[k], Wr1[o * 256 + k], acc);
    m_s[o] = fmaxf(acc, 0.f);
    __syncthreads();
    int ih = is_head[0];
    int nid = ih ? tids[b] : hids[b];
#pragma unroll
    for (int q = 0; q < 4; ++q) {
        int n = o + 64 * q;
        float r = br2[n];
        for (int jj = 0; jj < 64; ++jj) r = fmaf(m_s[jj], Wr2[n * 64 + jj], r);
        float hv = hn[(size_t)nid * 256 + n];
        tvec[b * 256 + n] = ih ? (hv - r) : (hv + r);
    }
}

__global__ __launch_bounds__(256) void k_score(
    const float* __restrict__ hn, const float* __restrict__ tvec,
    float* __restrict__ score)
{
    int p = blockIdx.x * 4 + (threadIdx.x >> 6);
    if (p >= BQ * (NN / BQ)) return;
    int l = threadIdx.x & 63;
    int b = p / (NN / BQ);
    int j = p - b * (NN / BQ);
    int idx = (b * NN + 32 * j) / BQ;   // faithful repeat_interleave indexing
    float ssum = 0.f;
#pragma unroll
    for (int q = 0; q < 4; ++q) {
        float df = hn[(size_t)idx * 256 + l + 64 * q] - tvec[b * 256 + l + 64 * q];
        ssum = fmaf(df, df, ssum);
    }
#pragma unroll
    for (int off = 32; off >= 1; off >>= 1) ssum += __shfl_xor(ssum, off, 64);
    float dist = sqrtf(ssum);
    float sc = 1.f / (1.f + expf(dist - 12.f));
    if (l < 32) score[(size_t)b * NN + 32 * j + l] = sc;
}

// ---------------- launch ----------------
extern "C" void kernel_launch(void* const* d_in, const int* in_sizes, int n_in,
                              void* d_out, int out_size, void* d_ws, size_t ws_size,
                              hipStream_t stream)
{
    const float* node_embs = (const float*)d_in[0];
    const float* edge_embs = (const float*)d_in[1];
    const float* W_O1 = (const float*)d_in[2];  const float* b_O1 = (const float*)d_in[3];
    const float* W_I1 = (const float*)d_in[4];  const float* b_I1 = (const float*)d_in[5];
    const float* W_S1 = (const float*)d_in[6];  const float* b_S1 = (const float*)d_in[7];
    const float* bn1_g = (const float*)d_in[8]; const float* bn1_b = (const float*)d_in[9];
    const float* bn1_m = (const float*)d_in[10];const float* bn1_v = (const float*)d_in[11];
    const float* Wr1 = (const float*)d_in[12];  const float* br1 = (const float*)d_in[13];
    const float* W_O2 = (const float*)d_in[14]; const float* b_O2 = (const float*)d_in[15];
    const float* W_I2 = (const float*)d_in[16]; const float* b_I2 = (const float*)d_in[17];
    const float* W_S2 = (const float*)d_in[18]; const float* b_S2 = (const float*)d_in[19];
    const float* bn2_g = (const float*)d_in[20];const float* bn2_b = (const float*)d_in[21];
    const float* bn2_m = (const float*)d_in[22];const float* bn2_v = (const float*)d_in[23];
    const float* Wr2 = (const float*)d_in[24];  const float* br2 = (const float*)d_in[25];
    const int* src = (const int*)d_in[26];
    const int* dst = (const int*)d_in[27];
    const int* evid = (const int*)d_in[28];
    const int* hids = (const int*)d_in[29];
    const int* rids = (const int*)d_in[30];
    const int* tids = (const int*)d_in[31];
    const int* upd = (const int*)d_in[32];
    const int* ihead = (const int*)d_in[33];

    float* ws = (float*)d_ws;
    float* C1   = ws;                      // 20000*192  : [hO1 | hI1 | hS1raw]
    float* A2   = C1 + 3840000;            // 20000*192  : [agg2O' | agg2I' | h1]
    float* E1   = A2 + 3840000;            // 500*256    : [eO1 | eI1 | (unused) | er1]
    unsigned short* Bn1 = (unsigned short*)(E1 + 128000);  // 256*256 bf16
    unsigned short* Bn2 = Bn1 + 65536;                     // 256*192 bf16
    float* degi = (float*)(Bn2 + 49152);   // 20000 (invdeg_in)
    float* dego = degi + 20000;            // 20000 (invdeg_out)
    float* s1   = dego + 20000;            // 64
    float* t1   = s1 + 64;                 // 64
    float* s2   = t1 + 64;                 // 256
    float* t2   = s2 + 256;                // 256
    float* tvec = t2 + 256;                // 32*256

    unsigned* R = (unsigned*)(tvec + 8192);// 2*NE packed records (16B-aligned)
    int* cnt    = (int*)(R + 2 * NE);      // 2*NN
    int* offc   = cnt + 2 * NN;            // 2*NN+1
    int* cur    = offc + 2 * NN + 1;       // 2*NN
    int* bsum   = cur + 2 * NN;            // NB

    float* hn    = (float*)d_out;                       // 20000*256
    float* score = hn + (size_t)NN * EMBD;              // 32*20000

    hipMemsetAsync(cnt, 0, (size_t)2 * NN * 4, stream);

    k_buildBn<<<NBLK_BN + 2, 256, 0, stream>>>(
        W_O1, W_I1, W_S1, Wr1, W_O2, W_I2, W_S2, Bn1, Bn2,
        b_O1, b_I1, b_S1, bn1_g, bn1_b, bn1_m, bn1_v,
        b_O2, b_I2, b_S2, bn2_g, bn2_b, bn2_m, bn2_v,
        s1, t1, s2, t2);

    // CSR build
    k_hist<<<(NE + 255) / 256, 256, 0, stream>>>(src, dst, cnt);
    k_scanA<<<NB, 256, 0, stream>>>(cnt, bsum);
    k_scanB<<<1, 64, 0, stream>>>(bsum);
    k_scanC<<<NB, 256, 0, stream>>>(cnt, bsum, offc, cur, degi, dego);
    k_scatter<<<(NE + 255) / 256, 256, 0, stream>>>(src, dst, evid, cur, R);

    // C1 = node_embs @ Bn1[0:192]^T   (M=20000, K=256)
    gemm_mfma<<<dim3(313, 3), 256, 0, stream>>>(node_embs, NN, 256, 256, Bn1,
                                                C1, 192, 0, nullptr, nullptr, nullptr, nullptr);
    // E1 = edge_embs @ Bn1^T, fused er1 on cols [192,256)   (M=500, K=256)
    gemm_mfma<<<dim3(8, 4), 256, 0, stream>>>(edge_embs, NR, 256, 256, Bn1,
                                              E1, 256, 1, br1, nullptr, nullptr, nullptr);

    // layer-1 aggregation + combine (writes h1 into A2 cols [128,192))
    k_gather1<<<NN / 4, 256, 0, stream>>>(offc, R, C1, E1, degi, dego, s1, t1, A2);
    // layer-2 aggregation (writes A2 cols [0,128))
    k_gather2<<<NN / 4, 256, 0, stream>>>(offc, R, A2, E1, degi, dego, A2);

    // hn = tanh((A2 @ Bn2^T) * s2 + t2)  (or node_embs if !upd)  (M=20000, K=192)
    gemm_mfma<<<dim3(313, 4), 256, 0, stream>>>(A2, NN, 192, 192, Bn2,
                                                hn, 256, 2, s2, t2, node_embs, upd);

    k_rels<<<BQ, 64, 0, stream>>>(edge_embs, Wr1, br1, Wr2, br2,
                                  hids, rids, tids, ihead, hn, tvec);
    k_score<<<(BQ * (NN / BQ)) / 4, 256, 0, stream>>>(hn, tvec, score);
}